// Round 9
// baseline (632.663 us; speedup 1.0000x reference)
//
#include <hip/hip_runtime.h>
#include <cstdint>

static constexpr int N = 20000;
static constexpr int E = 320000;
static constexpr int R = 8;
static constexpr int H = 4;
static constexpr int C = 256;

using short8 = __attribute__((ext_vector_type(8))) short;
using f32x4  = __attribute__((ext_vector_type(4))) float;

__device__ __forceinline__ float lrelu(float x, float s) { return x >= 0.f ? x : s * x; }
__device__ __forceinline__ unsigned short f2bf(float f) {
    unsigned u = __float_as_uint(f);
    unsigned r = (u + 0x7FFFu + ((u >> 16) & 1u)) >> 16;
    return (unsigned short)r;
}
__device__ __forceinline__ float bf2f(unsigned short s) {
    return __uint_as_float(((unsigned)s) << 16);
}

// ---------------- CSR build ----------------
__global__ void k_zero_int(int* p, int n) {
    int i = blockIdx.x * blockDim.x + threadIdx.x;
    if (i < n) p[i] = 0;
}

__global__ void k_count(const int* __restrict__ ei, int* __restrict__ cnt) {
    int e = blockIdx.x * blockDim.x + threadIdx.x;
    if (e < E) atomicAdd(&cnt[ei[E + e]], 1);
}

// exclusive scan of cnt -> rowptr; also emits cursor copy and dis = rsqrt(cnt+1)
__global__ __launch_bounds__(1024) void k_scan(const int* __restrict__ cnt,
                                               int* __restrict__ rowptr,
                                               int* __restrict__ cursor,
                                               float* __restrict__ dis) {
    __shared__ int part[1024];
    const int CH = (N + 1023) / 1024;  // 20
    int t = threadIdx.x;
    int base = t * CH;
    int sum = 0;
    for (int j = 0; j < CH; ++j) {
        int idx = base + j;
        if (idx < N) sum += cnt[idx];
    }
    part[t] = sum;
    __syncthreads();
    for (int off = 1; off < 1024; off <<= 1) {
        int v = 0;
        if (t >= off) v = part[t - off];
        __syncthreads();
        if (t >= off) part[t] += v;
        __syncthreads();
    }
    int run = part[t] - sum;
    for (int j = 0; j < CH; ++j) {
        int idx = base + j;
        if (idx < N) {
            int cv = cnt[idx];
            rowptr[idx] = run;
            cursor[idx] = run;
            dis[idx] = rsqrtf((float)cv + 1.0f);
            run += cv;
        }
    }
    if (t == 1023) rowptr[N] = part[1023];
}

// csr_se packs (edge_type<<16)|src ; csr_eid keeps original edge id
__global__ void k_scatter(const int* __restrict__ ei, const int* __restrict__ et,
                          int* __restrict__ cursor, int* __restrict__ csr_se,
                          int* __restrict__ csr_eid) {
    int e = blockIdx.x * blockDim.x + threadIdx.x;
    if (e >= E) return;
    int d = ei[E + e];
    int pos = atomicAdd(&cursor[d], 1);
    csr_se[pos] = (et[e] << 16) | ei[e];
    csr_eid[pos] = e;
}

// ---------------- GCN ----------------
__global__ void k_h1(const float* __restrict__ x, const float* __restrict__ W,
                     float* __restrict__ h) {
    int idx = blockIdx.x * blockDim.x + threadIdx.x;
    if (idx >= N * 32) return;
    int n = idx >> 5, f = idx & 31;
    const float* xr = x + n * 4;
    float acc = 0.f;
#pragma unroll
    for (int c = 0; c < 4; ++c) acc += xr[c] * W[c * 32 + f];
    h[idx] = acc;
}

__global__ void k_agg32(const int* __restrict__ rowptr, const int* __restrict__ csr_se,
                        const float* __restrict__ dis, const float* __restrict__ h,
                        const float* __restrict__ b, float* __restrict__ c) {
    int idx = blockIdx.x * blockDim.x + threadIdx.x;
    if (idx >= N * 32) return;
    int d = idx >> 5, f = idx & 31;
    int beg = rowptr[d], end = rowptr[d + 1];
    float acc = 0.f;
    for (int i = beg; i < end; ++i) {
        int s = csr_se[i] & 0xFFFF;
        acc += dis[s] * h[s * 32 + f];
    }
    float dd = dis[d];
    c[idx] = dd * acc + dd * dd * h[idx] + b[f];
}

// h2 (bf16) + kg copy into x0/xb0, one dispatch
__global__ void k_h2kg(const float* __restrict__ c1, const float* __restrict__ W,
                       const float* __restrict__ kg, unsigned short* __restrict__ h,
                       float* __restrict__ x0, unsigned short* __restrict__ xb0) {
    int idx = blockIdx.x * blockDim.x + threadIdx.x;
    if (idx >= N * 128) return;
    int n = idx >> 7, f = idx & 127;
    const float* cr = c1 + n * 32;
    float acc = 0.f;
    for (int c = 0; c < 32; ++c) acc += lrelu(cr[c], 0.01f) * W[c * 128 + f];
    h[idx] = f2bf(acc);
    float v = kg[idx];
    x0[n * 256 + f] = v;
    xb0[n * 256 + f] = f2bf(v);
}

__global__ void k_agg128(const int* __restrict__ rowptr, const int* __restrict__ csr_se,
                         const float* __restrict__ dis,
                         const unsigned short* __restrict__ h,
                         const float* __restrict__ b, float* __restrict__ x0,
                         unsigned short* __restrict__ xb0) {
    int idx = blockIdx.x * blockDim.x + threadIdx.x;
    if (idx >= N * 128) return;
    int d = idx >> 7, f = idx & 127;
    int beg = rowptr[d], end = rowptr[d + 1];
    float acc = 0.f;
    int i = beg;
    for (; i + 2 <= end; i += 2) {
        int s0 = csr_se[i] & 0xFFFF;
        int s1 = csr_se[i + 1] & 0xFFFF;
        float d0 = dis[s0], d1 = dis[s1];
        float v0 = bf2f(h[s0 * 128 + f]), v1 = bf2f(h[s1 * 128 + f]);
        acc += d0 * v0 + d1 * v1;
    }
    if (i < end) {
        int s = csr_se[i] & 0xFFFF;
        acc += dis[s] * bf2f(h[s * 128 + f]);
    }
    float dd = dis[d];
    float v = dd * acc + dd * dd * bf2f(h[d * 128 + f]) + b[f];
    x0[d * 256 + 128 + f] = v;
    xb0[d * 256 + 128 + f] = f2bf(v);
}

// ---------------- RGAT attention ----------------
// fused W@q / W@k projection, written directly as bf16 [n][k] (n<32: q, else k)
__global__ void k_wqkb(const float* __restrict__ W, const float* __restrict__ q,
                       const float* __restrict__ kmat, unsigned short* __restrict__ wqkb) {
    int idx = blockIdx.x * blockDim.x + threadIdx.x;
    if (idx >= 64 * 256) return;
    int n = idx >> 8, i = idx & 255;
    int m = n & 31;
    int r = m >> 2, h = m & 3;
    const float* src = (n < 32) ? q : kmat;
    const float* wr = W + ((long)r * 256 + i) * 256;
    float acc = 0.f;
    for (int o = 0; o < 256; ++o) acc += wr[o] * src[o * 4 + h];
    wqkb[n * 256 + i] = f2bf(acc);
}

// qn|kn = xb @ wqkb^T via MFMA.  Block: 256 thr = 4 waves, 64 rows per block.
#define QP 264
__global__ __launch_bounds__(256) void k_qnkn_mfma(
    const unsigned short* __restrict__ xb, const unsigned short* __restrict__ wqkb,
    float* __restrict__ qn, float* __restrict__ kn)
{
    __shared__ unsigned short Ws[64 * QP];
    int t = threadIdx.x;
    {
        int r = t >> 2, off = (t & 3) * 64;
#pragma unroll
        for (int i = 0; i < 8; ++i)
            *(uint4*)(&Ws[r * QP + off + i * 8]) =
                *(const uint4*)(wqkb + r * 256 + off + i * 8);
    }
    __syncthreads();
    int wave = t >> 6, lane = t & 63;
    int lrow = lane & 15, kq = lane >> 4;
    int mw = blockIdx.x * 64 + wave * 16;
    int gm = mw + lrow;
    int gmc = gm < N ? gm : N - 1;

    f32x4 acc[4];
#pragma unroll
    for (int j = 0; j < 4; ++j) acc[j] = (f32x4){0.f, 0.f, 0.f, 0.f};

    for (int k0 = 0; k0 < 8; ++k0) {
        short8 af = *(const short8*)(xb + (size_t)gmc * 256 + k0 * 32 + kq * 8);
#pragma unroll
        for (int j = 0; j < 4; ++j) {
            short8 bf4 = *(const short8*)(&Ws[(j * 16 + lrow) * QP + k0 * 32 + kq * 8]);
            acc[j] = __builtin_amdgcn_mfma_f32_16x16x32_bf16(af, bf4, acc[j], 0, 0, 0);
        }
    }
#pragma unroll
    for (int j = 0; j < 4; ++j) {
        int col = j * 16 + lrow;
#pragma unroll
        for (int reg = 0; reg < 4; ++reg) {
            int gr = mw + kq * 4 + reg;
            if (gr < N) {
                if (col < 32) qn[gr * 32 + col] = acc[j][reg];
                else          kn[gr * 32 + (col - 32)] = acc[j][reg];
            }
        }
    }
}

// fused per-(node,head) softmax over incoming edges
__global__ void k_soft(const int* __restrict__ rowptr, const int* __restrict__ csr_se,
                       const int* __restrict__ csr_eid,
                       const float* __restrict__ qn, const float* __restrict__ kn,
                       float* __restrict__ alpha_csr, float* __restrict__ aout) {
    int idx = blockIdx.x * blockDim.x + threadIdx.x;
    if (idx >= N * H) return;
    int d = idx >> 2, h = idx & 3;
    int beg = rowptr[d], end = rowptr[d + 1];
    if (beg == end) return;
    float m = -1e30f;
    for (int i = beg; i < end; ++i) {
        int se = csr_se[i];
        int tt = se >> 16, s = se & 0xFFFF;
        float v = qn[d * 32 + tt * 4 + h] + kn[s * 32 + tt * 4 + h];
        v = lrelu(v, 0.2f);
        alpha_csr[i * 4 + h] = v;
        m = fmaxf(m, v);
    }
    float sum = 0.f;
    for (int i = beg; i < end; ++i) {
        float ex = expf(alpha_csr[i * 4 + h] - m);
        alpha_csr[i * 4 + h] = ex;
        sum += ex;
    }
    float inv = 1.f / sum;
    for (int i = beg; i < end; ++i) {
        float a = alpha_csr[i * 4 + h] * inv;
        alpha_csr[i * 4 + h] = a;
        aout[csr_eid[i] * 4 + h] = a;
    }
}

// Wt[z][n][k] = bf16(W[z][k][n])
__global__ void k_wconv(const float* __restrict__ W, unsigned short* __restrict__ Wt,
                        int zcnt) {
    int idx = blockIdx.x * blockDim.x + threadIdx.x;
    if (idx >= zcnt * 65536) return;
    int z = idx >> 16, k = (idx >> 8) & 255, n = idx & 255;
    Wt[((size_t)z << 16) + (n << 8) + k] = f2bf(W[idx]);
}

// ---------------- bf16 MFMA GEMM, XCD-swizzled grid, LDS-transpose epilogue ----
// If Cf==nullptr: Cbf[z][M][256] = bf16(A@B[z])      (coalesced uint4 stores)
// Else          : Cf = A@B[0] + bias + bias2          (coalesced float4 stores)
#define TM 128
#define TN 128
#define TK 32
#define LPP 40
#define EPI_P 136   // epilogue bf16 pitch (shorts): 272 B rows, 16B-aligned
#define EPI_PF 132  // epilogue fp32 pitch (floats): 528 B rows, 16B-aligned (>=128 cols!)
__global__ __launch_bounds__(256) void gemm_mfma3(
    const unsigned short* __restrict__ A, const unsigned short* __restrict__ Bt,
    unsigned short* __restrict__ Cbf, float* __restrict__ Cf,
    const float* __restrict__ bias, const float* __restrict__ bias2,
    int M, int NZ, int NT, int MT)
{
    __shared__ unsigned short Sh[2 * TM * LPP];  // 20.5 KB, reused by epilogue
    unsigned short* As = Sh;
    unsigned short* Bs = Sh + TM * LPP;

    int bi = blockIdx.x;
    int cx = bi & 7;
    int g = bi >> 3;
    int per = NZ * NT;
    int mh = g / per;
    int j  = g % per;
    int mt = mh * 8 + cx;
    if (mt >= MT) return;
    int z  = j % NZ;
    int nb = j / NZ;
    int m0 = mt * TM;
    int n0 = nb * TN;

    const unsigned short* Bz = Bt + ((size_t)z << 16);
    int t = threadIdx.x;
    int wave = t >> 6, lane = t & 63;
    int wr = wave >> 1, wc = wave & 1;
    int lrow = lane & 15, kq = lane >> 4;

    f32x4 acc[4][4];
#pragma unroll
    for (int i = 0; i < 4; ++i)
#pragma unroll
        for (int jj = 0; jj < 4; ++jj) acc[i][jj] = (f32x4){0.f, 0.f, 0.f, 0.f};

    for (int k0 = 0; k0 < 256; k0 += TK) {
#pragma unroll
        for (int i = 0; i < 2; ++i) {
            int cc = t + i * 256;
            int row = cc >> 2, kc = cc & 3;
            int gm = m0 + row;
            uint4 va = {0, 0, 0, 0};
            if (gm < M) va = *(const uint4*)(A + (size_t)gm * 256 + k0 + kc * 8);
            *(uint4*)(&As[row * LPP + kc * 8]) = va;
            uint4 vb = *(const uint4*)(Bz + (size_t)(n0 + row) * 256 + k0 + kc * 8);
            *(uint4*)(&Bs[row * LPP + kc * 8]) = vb;
        }
        __syncthreads();
        short8 af[4], bf4[4];
#pragma unroll
        for (int i = 0; i < 4; ++i)
            af[i] = *(const short8*)(&As[(wr * 64 + i * 16 + lrow) * LPP + kq * 8]);
#pragma unroll
        for (int jj = 0; jj < 4; ++jj)
            bf4[jj] = *(const short8*)(&Bs[(wc * 64 + jj * 16 + lrow) * LPP + kq * 8]);
#pragma unroll
        for (int i = 0; i < 4; ++i)
#pragma unroll
            for (int jj = 0; jj < 4; ++jj)
                acc[i][jj] = __builtin_amdgcn_mfma_f32_16x16x32_bf16(af[i], bf4[jj],
                                                                     acc[i][jj], 0, 0, 0);
        __syncthreads();
    }

    if (Cf) {
        // 4 chunks of 32 rows through LDS (fp32), pure coalesced stores
        float* Shf = (float*)Sh;
        for (int ch = 0; ch < 4; ++ch) {
            if (wr == (ch >> 1)) {
                int ibase = (ch & 1) * 2;
#pragma unroll
                for (int ii = 0; ii < 2; ++ii) {
#pragma unroll
                    for (int jj = 0; jj < 4; ++jj) {
                        int lc = wc * 64 + jj * 16 + lrow;
                        int gn = n0 + lc;
                        float bsum = bias[gn] + bias2[gn];
#pragma unroll
                        for (int reg = 0; reg < 4; ++reg) {
                            int lr = ii * 16 + kq * 4 + reg;
                            Shf[lr * EPI_PF + lc] = acc[ibase + ii][jj][reg] + bsum;
                        }
                    }
                }
            }
            __syncthreads();
            {
                int r = t >> 3, seg = t & 7;
                int gm2 = m0 + ch * 32 + r;
                if (gm2 < M) {
                    float* dst = Cf + (size_t)gm2 * 256 + n0 + seg * 16;
                    const float* srcp = Shf + r * EPI_PF + seg * 16;
#pragma unroll
                    for (int k = 0; k < 4; ++k)
                        *(float4*)(dst + k * 4) = *(const float4*)(srcp + k * 4);
                }
            }
            __syncthreads();
        }
    } else {
        // 2 chunks of 64 rows through LDS (bf16), coalesced uint4 stores
        for (int ch = 0; ch < 2; ++ch) {
            if (wr == ch) {
#pragma unroll
                for (int i = 0; i < 4; ++i)
#pragma unroll
                    for (int jj = 0; jj < 4; ++jj) {
                        int lc = wc * 64 + jj * 16 + lrow;
#pragma unroll
                        for (int reg = 0; reg < 4; ++reg) {
                            int lr = i * 16 + kq * 4 + reg;
                            Sh[lr * EPI_P + lc] = f2bf(acc[i][jj][reg]);
                        }
                    }
            }
            __syncthreads();
            {
                int r = t >> 2, seg = t & 3;
                int gm2 = m0 + ch * 64 + r;
                if (gm2 < M) {
                    unsigned short* dst = Cbf + ((size_t)z * M + gm2) * 256 + n0 + seg * 32;
                    const unsigned short* srcp = Sh + r * EPI_P + seg * 32;
#pragma unroll
                    for (int k = 0; k < 4; ++k)
                        *(uint4*)(dst + k * 8) = *(const uint4*)(srcp + k * 8);
                }
            }
            __syncthreads();
        }
    }
}

// ---------------- message aggregation (CSR gather, unroll-2) ----------------
__global__ void k_msg_gather(const int* __restrict__ rowptr, const int* __restrict__ csr_se,
                             const float* __restrict__ alpha_csr,
                             const unsigned short* __restrict__ xw,
                             const float* __restrict__ bias, float* __restrict__ out,
                             unsigned short* __restrict__ xbout,
                             int r0, int r1, int first, int act) {
    int gid = blockIdx.x * blockDim.x + threadIdx.x;
    int node = gid >> 6, lane = gid & 63;
    if (node >= N) return;
    int hsel = lane >> 4;
    float ax = 0.f, ay = 0.f, az = 0.f, aw = 0.f;
    int beg = rowptr[node], end = rowptr[node + 1];
    int i = beg;
    for (; i + 2 <= end; i += 2) {
        int se0 = csr_se[i], se1 = csr_se[i + 1];
        int t0 = se0 >> 16, t1 = se1 >> 16;
        float a0 = alpha_csr[i * 4 + hsel];
        float a1v = alpha_csr[(i + 1) * 4 + hsel];
        if (t0 >= r0 && t0 < r1) {
            int s = se0 & 0xFFFF;
            uint2 p = *(const uint2*)(xw + ((size_t)(t0 - r0) * N + s) * 256 + lane * 4);
            ax += a0 * __uint_as_float(p.x << 16);
            ay += a0 * __uint_as_float(p.x & 0xFFFF0000u);
            az += a0 * __uint_as_float(p.y << 16);
            aw += a0 * __uint_as_float(p.y & 0xFFFF0000u);
        }
        if (t1 >= r0 && t1 < r1) {
            int s = se1 & 0xFFFF;
            uint2 p = *(const uint2*)(xw + ((size_t)(t1 - r0) * N + s) * 256 + lane * 4);
            ax += a1v * __uint_as_float(p.x << 16);
            ay += a1v * __uint_as_float(p.x & 0xFFFF0000u);
            az += a1v * __uint_as_float(p.y << 16);
            aw += a1v * __uint_as_float(p.y & 0xFFFF0000u);
        }
    }
    if (i < end) {
        int se = csr_se[i];
        int tt = se >> 16;
        if (tt >= r0 && tt < r1) {
            int s = se & 0xFFFF;
            float a = alpha_csr[i * 4 + hsel];
            uint2 p = *(const uint2*)(xw + ((size_t)(tt - r0) * N + s) * 256 + lane * 4);
            ax += a * __uint_as_float(p.x << 16);
            ay += a * __uint_as_float(p.x & 0xFFFF0000u);
            az += a * __uint_as_float(p.y << 16);
            aw += a * __uint_as_float(p.y & 0xFFFF0000u);
        }
    }
    float* o = out + (size_t)node * 256 + lane * 4;
    float vx, vy, vz, vw;
    if (first) {
        const float4 b = ((const float4*)bias)[lane];
        vx = ax + b.x; vy = ay + b.y; vz = az + b.z; vw = aw + b.w;
    } else {
        vx = o[0] + ax; vy = o[1] + ay; vz = o[2] + az; vw = o[3] + aw;
    }
    if (act) {
        vx = lrelu(vx, 0.01f); vy = lrelu(vy, 0.01f);
        vz = lrelu(vz, 0.01f); vw = lrelu(vw, 0.01f);
        unsigned short* xo = xbout + (size_t)node * 256 + lane * 4;
        xo[0] = f2bf(vx); xo[1] = f2bf(vy); xo[2] = f2bf(vz); xo[3] = f2bf(vw);
    }
    o[0] = vx; o[1] = vy; o[2] = vz; o[3] = vw;
}

extern "C" void kernel_launch(void* const* d_in, const int* in_sizes, int n_in,
                              void* d_out, int out_size, void* d_ws, size_t ws_size,
                              hipStream_t stream) {
    const float* kg   = (const float*)d_in[0];
    const float* cc0  = (const float*)d_in[1];
    const float* gw1  = (const float*)d_in[2];
    const float* gb1  = (const float*)d_in[3];
    const float* gw2  = (const float*)d_in[4];
    const float* gb2  = (const float*)d_in[5];
    const float* r1w  = (const float*)d_in[6];
    const float* r1q  = (const float*)d_in[7];
    const float* r1k  = (const float*)d_in[8];
    const float* r1b  = (const float*)d_in[9];
    const float* r2w  = (const float*)d_in[10];
    const float* r2q  = (const float*)d_in[11];
    const float* r2k  = (const float*)d_in[12];
    const float* r2b  = (const float*)d_in[13];
    const float* linw = (const float*)d_in[14];
    const float* linb = (const float*)d_in[15];
    const int*   ei   = (const int*)d_in[16];
    const int*   et   = (const int*)d_in[17];

    float* out = (float*)d_out;
    float* a1  = out + (size_t)N * C;
    float* a2  = a1 + (size_t)E * H;

    float* ws = (float*)d_ws;
    size_t off = 0;
    float* dis  = ws + off; off += N;
    float* h1   = ws + off; off += (size_t)N * 32;
    float* c1   = ws + off; off += (size_t)N * 32;
    unsigned short* h2b = (unsigned short*)(ws + off); off += (size_t)N * 64;
    float* x0   = ws + off; off += (size_t)N * C;
    float* hmid = ws + off; off += (size_t)N * C;
    float* qn   = ws + off; off += (size_t)N * R * H;
    float* kn   = ws + off; off += (size_t)N * R * H;
    int* cnt     = (int*)(ws + off); off += N;
    int* rowptr  = (int*)(ws + off); off += N + 1;
    int* cursor  = (int*)(ws + off); off += N;
    int* csr_se  = (int*)(ws + off); off += E;
    int* csr_eid = (int*)(ws + off); off += E;
    float* alpha = ws + off; off += (size_t)E * H;
    unsigned short* xb0 = (unsigned short*)(ws + off); off += (size_t)N * 128;
    unsigned short* xb1 = (unsigned short*)(ws + off); off += (size_t)N * 128;
    unsigned short* wt  = (unsigned short*)(ws + off); off += (size_t)R * 32768;
    unsigned short* wtl = (unsigned short*)(ws + off); off += 32768;
    unsigned short* wqkb = (unsigned short*)(ws + off); off += 8192;
    unsigned short* xwb = (unsigned short*)(ws + off);

    size_t fixedB = off * 4;
    int K = R;
    if (ws_size > fixedB) {
        size_t kmax = (ws_size - fixedB) / ((size_t)N * C * 2);
        if (kmax < (size_t)K) K = (int)kmax;
    } else {
        K = 1;
    }
    if (K < 1) K = 1;

    const int B = 256;
    auto cdiv = [](long a, long b) { return (int)((a + b - 1) / b); };
    const int MT = cdiv(N, TM);  // 157 m-tiles

    // ---- CSR build ----
    k_zero_int<<<cdiv(N, B), B, 0, stream>>>(cnt, N);
    k_count<<<cdiv(E, B), B, 0, stream>>>(ei, cnt);
    k_scan<<<1, 1024, 0, stream>>>(cnt, rowptr, cursor, dis);
    k_scatter<<<cdiv(E, B), B, 0, stream>>>(ei, et, cursor, csr_se, csr_eid);

    // ---- GCN ----
    k_h1<<<cdiv((long)N * 32, B), B, 0, stream>>>(cc0, gw1, h1);
    k_agg32<<<cdiv((long)N * 32, B), B, 0, stream>>>(rowptr, csr_se, dis, h1, gb1, c1);
    k_h2kg<<<cdiv((long)N * 128, B), B, 0, stream>>>(c1, gw2, kg, h2b, x0, xb0);
    k_agg128<<<cdiv((long)N * 128, B), B, 0, stream>>>(rowptr, csr_se, dis, h2b,
                                                       gb2, x0, xb0);

    auto rgat = [&](unsigned short* xb, const float* W,
                    const float* q, const float* kk, const float* b,
                    float* obuf, unsigned short* xbout, float* aout,
                    int first, int act) {
        k_wqkb<<<cdiv((long)64 * 256, B), B, 0, stream>>>(W, q, kk, wqkb);
        k_qnkn_mfma<<<cdiv(N, 64), B, 0, stream>>>(xb, wqkb, qn, kn);
        k_soft<<<cdiv((long)N * H, B), B, 0, stream>>>(rowptr, csr_se, csr_eid,
                                                       qn, kn, alpha, aout);
        k_wconv<<<cdiv((long)R * 65536, B), B, 0, stream>>>(W, wt, R);
        for (int r0 = 0; r0 < R; r0 += K) {
            int kc = (R - r0) < K ? (R - r0) : K;
            int gx = 8 * kc * (C / TN) * cdiv(MT, 8);
            gemm_mfma3<<<gx, 256, 0, stream>>>(xb, wt + ((size_t)r0 << 16), xwb,
                                               nullptr, nullptr, nullptr,
                                               N, kc, C / TN, MT);
            int last = (r0 + kc >= R) ? 1 : 0;
            k_msg_gather<<<cdiv((long)N * 64, B), B, 0, stream>>>(
                rowptr, csr_se, alpha, xwb, b, obuf, xbout, r0, r0 + kc,
                (first && r0 == 0) ? 1 : 0, act && last);
        }
    };

    // layer 1: hmid = bias + messages, leaky fused, emits xb1 bf16
    rgat(xb0, r1w, r1q, r1k, r1b, hmid, xb1, a1, 1, 1);

    // residual linear BEFORE layer-2 messages: out = x0@linw + (linb + r2b)
    k_wconv<<<cdiv((long)65536, B), B, 0, stream>>>(linw, wtl, 1);
    {
        int gx = 8 * 1 * (C / TN) * cdiv(MT, 8);
        gemm_mfma3<<<gx, 256, 0, stream>>>(xb0, wtl, nullptr, out, linb, r2b,
                                           N, 1, C / TN, MT);
    }

    // layer 2: out += messages (bias already folded into linear epilogue)
    rgat(xb1, r2w, r2q, r2k, r2b, out, nullptr, a2, 0, 0);
}

// Round 10
// 560.754 us; speedup vs baseline: 1.1282x; 1.1282x over previous
//
#include <hip/hip_runtime.h>
#include <cstdint>

static constexpr int N = 20000;
static constexpr int E = 320000;
static constexpr int R = 8;
static constexpr int H = 4;
static constexpr int C = 256;

using short8 = __attribute__((ext_vector_type(8))) short;
using f32x4  = __attribute__((ext_vector_type(4))) float;

__device__ __forceinline__ float lrelu(float x, float s) { return x >= 0.f ? x : s * x; }
__device__ __forceinline__ unsigned short f2bf(float f) {
    unsigned u = __float_as_uint(f);
    unsigned r = (u + 0x7FFFu + ((u >> 16) & 1u)) >> 16;
    return (unsigned short)r;
}
__device__ __forceinline__ float bf2f(unsigned short s) {
    return __uint_as_float(((unsigned)s) << 16);
}

// ---------------- CSR build ----------------
__global__ void k_zero_int(int* p, int n) {
    int i = blockIdx.x * blockDim.x + threadIdx.x;
    if (i < n) p[i] = 0;
}

__global__ void k_count(const int* __restrict__ ei, int* __restrict__ cnt) {
    int e = blockIdx.x * blockDim.x + threadIdx.x;
    if (e < E) atomicAdd(&cnt[ei[E + e]], 1);
}

// exclusive scan of cnt -> rowptr; also emits cursor copy and dis = rsqrt(cnt+1)
__global__ __launch_bounds__(1024) void k_scan(const int* __restrict__ cnt,
                                               int* __restrict__ rowptr,
                                               int* __restrict__ cursor,
                                               float* __restrict__ dis) {
    __shared__ int part[1024];
    const int CH = (N + 1023) / 1024;  // 20
    int t = threadIdx.x;
    int base = t * CH;
    int sum = 0;
    for (int j = 0; j < CH; ++j) {
        int idx = base + j;
        if (idx < N) sum += cnt[idx];
    }
    part[t] = sum;
    __syncthreads();
    for (int off = 1; off < 1024; off <<= 1) {
        int v = 0;
        if (t >= off) v = part[t - off];
        __syncthreads();
        if (t >= off) part[t] += v;
        __syncthreads();
    }
    int run = part[t] - sum;
    for (int j = 0; j < CH; ++j) {
        int idx = base + j;
        if (idx < N) {
            int cv = cnt[idx];
            rowptr[idx] = run;
            cursor[idx] = run;
            dis[idx] = rsqrtf((float)cv + 1.0f);
            run += cv;
        }
    }
    if (t == 1023) rowptr[N] = part[1023];
}

// csr_se packs (edge_type<<16)|src ; csr_eid keeps original edge id
__global__ void k_scatter(const int* __restrict__ ei, const int* __restrict__ et,
                          int* __restrict__ cursor, int* __restrict__ csr_se,
                          int* __restrict__ csr_eid) {
    int e = blockIdx.x * blockDim.x + threadIdx.x;
    if (e >= E) return;
    int d = ei[E + e];
    int pos = atomicAdd(&cursor[d], 1);
    csr_se[pos] = (et[e] << 16) | ei[e];
    csr_eid[pos] = e;
}

// ---------------- GCN ----------------
__global__ void k_h1(const float* __restrict__ x, const float* __restrict__ W,
                     float* __restrict__ h) {
    int idx = blockIdx.x * blockDim.x + threadIdx.x;
    if (idx >= N * 32) return;
    int n = idx >> 5, f = idx & 31;
    const float* xr = x + n * 4;
    float acc = 0.f;
#pragma unroll
    for (int c = 0; c < 4; ++c) acc += xr[c] * W[c * 32 + f];
    h[idx] = acc;
}

__global__ void k_agg32(const int* __restrict__ rowptr, const int* __restrict__ csr_se,
                        const float* __restrict__ dis, const float* __restrict__ h,
                        const float* __restrict__ b, float* __restrict__ c) {
    int idx = blockIdx.x * blockDim.x + threadIdx.x;
    if (idx >= N * 32) return;
    int d = idx >> 5, f = idx & 31;
    int beg = rowptr[d], end = rowptr[d + 1];
    float acc = 0.f;
    for (int i = beg; i < end; ++i) {
        int s = csr_se[i] & 0xFFFF;
        acc += dis[s] * h[s * 32 + f];
    }
    float dd = dis[d];
    c[idx] = dd * acc + dd * dd * h[idx] + b[f];
}

// h2 (bf16) + kg copy into x0/xb0, one dispatch
__global__ void k_h2kg(const float* __restrict__ c1, const float* __restrict__ W,
                       const float* __restrict__ kg, unsigned short* __restrict__ h,
                       float* __restrict__ x0, unsigned short* __restrict__ xb0) {
    int idx = blockIdx.x * blockDim.x + threadIdx.x;
    if (idx >= N * 128) return;
    int n = idx >> 7, f = idx & 127;
    const float* cr = c1 + n * 32;
    float acc = 0.f;
    for (int c = 0; c < 32; ++c) acc += lrelu(cr[c], 0.01f) * W[c * 128 + f];
    h[idx] = f2bf(acc);
    float v = kg[idx];
    x0[n * 256 + f] = v;
    xb0[n * 256 + f] = f2bf(v);
}

__global__ void k_agg128(const int* __restrict__ rowptr, const int* __restrict__ csr_se,
                         const float* __restrict__ dis,
                         const unsigned short* __restrict__ h,
                         const float* __restrict__ b, float* __restrict__ x0,
                         unsigned short* __restrict__ xb0) {
    int idx = blockIdx.x * blockDim.x + threadIdx.x;
    if (idx >= N * 128) return;
    int d = idx >> 7, f = idx & 127;
    int beg = rowptr[d], end = rowptr[d + 1];
    float acc = 0.f;
    int i = beg;
    for (; i + 2 <= end; i += 2) {
        int s0 = csr_se[i] & 0xFFFF;
        int s1 = csr_se[i + 1] & 0xFFFF;
        float d0 = dis[s0], d1 = dis[s1];
        float v0 = bf2f(h[s0 * 128 + f]), v1 = bf2f(h[s1 * 128 + f]);
        acc += d0 * v0 + d1 * v1;
    }
    if (i < end) {
        int s = csr_se[i] & 0xFFFF;
        acc += dis[s] * bf2f(h[s * 128 + f]);
    }
    float dd = dis[d];
    float v = dd * acc + dd * dd * bf2f(h[d * 128 + f]) + b[f];
    x0[d * 256 + 128 + f] = v;
    xb0[d * 256 + 128 + f] = f2bf(v);
}

// ---------------- RGAT attention ----------------
// fused W@q / W@k projection, written directly as bf16 [n][k] (n<32: q, else k)
__global__ void k_wqkb(const float* __restrict__ W, const float* __restrict__ q,
                       const float* __restrict__ kmat, unsigned short* __restrict__ wqkb) {
    int idx = blockIdx.x * blockDim.x + threadIdx.x;
    if (idx >= 64 * 256) return;
    int n = idx >> 8, i = idx & 255;
    int m = n & 31;
    int r = m >> 2, h = m & 3;
    const float* src = (n < 32) ? q : kmat;
    const float* wr = W + ((long)r * 256 + i) * 256;
    float acc = 0.f;
    for (int o = 0; o < 256; ++o) acc += wr[o] * src[o * 4 + h];
    wqkb[n * 256 + i] = f2bf(acc);
}

// qn|kn = xb @ wqkb^T via MFMA.  Block: 256 thr = 4 waves, 64 rows per block.
#define QP 264
__global__ __launch_bounds__(256) void k_qnkn_mfma(
    const unsigned short* __restrict__ xb, const unsigned short* __restrict__ wqkb,
    float* __restrict__ qn, float* __restrict__ kn)
{
    __shared__ unsigned short Ws[64 * QP];
    int t = threadIdx.x;
    {
        int r = t >> 2, off = (t & 3) * 64;
#pragma unroll
        for (int i = 0; i < 8; ++i)
            *(uint4*)(&Ws[r * QP + off + i * 8]) =
                *(const uint4*)(wqkb + r * 256 + off + i * 8);
    }
    __syncthreads();
    int wave = t >> 6, lane = t & 63;
    int lrow = lane & 15, kq = lane >> 4;
    int mw = blockIdx.x * 64 + wave * 16;
    int gm = mw + lrow;
    int gmc = gm < N ? gm : N - 1;

    f32x4 acc[4];
#pragma unroll
    for (int j = 0; j < 4; ++j) acc[j] = (f32x4){0.f, 0.f, 0.f, 0.f};

    for (int k0 = 0; k0 < 8; ++k0) {
        short8 af = *(const short8*)(xb + (size_t)gmc * 256 + k0 * 32 + kq * 8);
#pragma unroll
        for (int j = 0; j < 4; ++j) {
            short8 bf4 = *(const short8*)(&Ws[(j * 16 + lrow) * QP + k0 * 32 + kq * 8]);
            acc[j] = __builtin_amdgcn_mfma_f32_16x16x32_bf16(af, bf4, acc[j], 0, 0, 0);
        }
    }
#pragma unroll
    for (int j = 0; j < 4; ++j) {
        int col = j * 16 + lrow;
#pragma unroll
        for (int reg = 0; reg < 4; ++reg) {
            int gr = mw + kq * 4 + reg;
            if (gr < N) {
                if (col < 32) qn[gr * 32 + col] = acc[j][reg];
                else          kn[gr * 32 + (col - 32)] = acc[j][reg];
            }
        }
    }
}

// wave-per-node softmax: lanes = 16 edge-slots x 4 heads, shuffle reductions.
// alpha regs cover deg<=64; recompute fallback beyond.
__global__ void k_soft(const int* __restrict__ rowptr, const int* __restrict__ csr_se,
                       const int* __restrict__ csr_eid,
                       const float* __restrict__ qn, const float* __restrict__ kn,
                       float* __restrict__ alpha_csr, float* __restrict__ aout) {
    int wid = (blockIdx.x * blockDim.x + threadIdx.x) >> 6;
    int lane = threadIdx.x & 63;
    if (wid >= N) return;
    int d = wid;
    int beg = rowptr[d], end = rowptr[d + 1];
    if (beg >= end) return;
    int slot = lane >> 2, h = lane & 3;
    int nc = (end - beg + 15) >> 4;
    const float* qrow = qn + d * 32;

    auto rawv = [&](int i) {
        int se = csr_se[i];
        int tt = se >> 16, s = se & 0xFFFF;
        return lrelu(qrow[tt * 4 + h] + kn[s * 32 + tt * 4 + h], 0.2f);
    };

    float av[4];
    float m = -1e30f;
    for (int c = 0; c < nc; ++c) {
        int i = beg + c * 16 + slot;
        float v = (i < end) ? rawv(i) : -1e30f;
        if (c < 4) av[c] = v;
        m = fmaxf(m, v);
    }
    m = fmaxf(m, __shfl_xor(m, 4));
    m = fmaxf(m, __shfl_xor(m, 8));
    m = fmaxf(m, __shfl_xor(m, 16));
    m = fmaxf(m, __shfl_xor(m, 32));

    float sum = 0.f;
    for (int c = 0; c < nc; ++c) {
        int i = beg + c * 16 + slot;
        float ex = 0.f;
        if (i < end) {
            float v = (c < 4) ? av[c] : rawv(i);
            ex = expf(v - m);
        }
        if (c < 4) av[c] = ex;
        sum += ex;
    }
    sum += __shfl_xor(sum, 4);
    sum += __shfl_xor(sum, 8);
    sum += __shfl_xor(sum, 16);
    sum += __shfl_xor(sum, 32);
    float inv = 1.f / sum;

    for (int c = 0; c < nc; ++c) {
        int i = beg + c * 16 + slot;
        if (i < end) {
            float ex = (c < 4) ? av[c] : expf(rawv(i) - m);
            float a = ex * inv;
            alpha_csr[i * 4 + h] = a;        // coalesced: base + c*64 + lane
            aout[csr_eid[i] * 4 + h] = a;    // scatter (model output order)
        }
    }
}

// Wt[z][n][k] = bf16(W[z][k][n])  -- 64x64 LDS-tile transpose, coalesced both ways
#define WTP 72
__global__ __launch_bounds__(256) void k_wconv_t(const float* __restrict__ W,
                                                 unsigned short* __restrict__ Wt) {
    int bid = blockIdx.x;
    int z = bid >> 4;
    int tile = bid & 15;
    int k0 = (tile >> 2) * 64, n0 = (tile & 3) * 64;
    __shared__ unsigned short T[64 * WTP];
    int t = threadIdx.x;
    const float* Wz = W + ((size_t)z << 16);
    int r = t >> 4;
    int cs = (t & 15) * 4;
#pragma unroll
    for (int rr = 0; rr < 4; ++rr) {
        int k = r + rr * 16;
        float4 v = *(const float4*)(Wz + (size_t)(k0 + k) * 256 + n0 + cs);
        T[(cs + 0) * WTP + k] = f2bf(v.x);
        T[(cs + 1) * WTP + k] = f2bf(v.y);
        T[(cs + 2) * WTP + k] = f2bf(v.z);
        T[(cs + 3) * WTP + k] = f2bf(v.w);
    }
    __syncthreads();
    int n = t >> 2, ck = (t & 3) * 16;
    unsigned short* dst = Wt + ((size_t)z << 16) + (size_t)(n0 + n) * 256 + k0 + ck;
    const unsigned short* srcp = T + n * WTP + ck;
    *(uint4*)(dst) = *(const uint4*)(srcp);
    *(uint4*)(dst + 8) = *(const uint4*)(srcp + 8);
}

// ---------------- bf16 MFMA GEMM, XCD-swizzled grid, direct-store epilogue ----
// If Cf==nullptr: Cbf[z][M][256] = bf16(A@B[z]).  Else: Cf = A@B[0] + bias + bias2.
#define TM 128
#define TN 128
#define TK 32
#define LPP 40
__global__ __launch_bounds__(256) void gemm_mfma3(
    const unsigned short* __restrict__ A, const unsigned short* __restrict__ Bt,
    unsigned short* __restrict__ Cbf, float* __restrict__ Cf,
    const float* __restrict__ bias, const float* __restrict__ bias2,
    int M, int NZ, int NT, int MT)
{
    __shared__ unsigned short As[TM * LPP];
    __shared__ unsigned short Bs[TN * LPP];

    int bi = blockIdx.x;
    int cx = bi & 7;
    int g = bi >> 3;
    int per = NZ * NT;
    int mh = g / per;
    int j  = g % per;
    int mt = mh * 8 + cx;
    if (mt >= MT) return;
    int z  = j % NZ;
    int nb = j / NZ;
    int m0 = mt * TM;
    int n0 = nb * TN;

    const unsigned short* Bz = Bt + ((size_t)z << 16);
    int t = threadIdx.x;
    int wave = t >> 6, lane = t & 63;
    int wr = wave >> 1, wc = wave & 1;
    int lrow = lane & 15, kq = lane >> 4;

    f32x4 acc[4][4];
#pragma unroll
    for (int i = 0; i < 4; ++i)
#pragma unroll
        for (int jj = 0; jj < 4; ++jj) acc[i][jj] = (f32x4){0.f, 0.f, 0.f, 0.f};

    for (int k0 = 0; k0 < 256; k0 += TK) {
#pragma unroll
        for (int i = 0; i < 2; ++i) {
            int cc = t + i * 256;
            int row = cc >> 2, kc = cc & 3;
            int gm = m0 + row;
            uint4 va = {0, 0, 0, 0};
            if (gm < M) va = *(const uint4*)(A + (size_t)gm * 256 + k0 + kc * 8);
            *(uint4*)(&As[row * LPP + kc * 8]) = va;
            uint4 vb = *(const uint4*)(Bz + (size_t)(n0 + row) * 256 + k0 + kc * 8);
            *(uint4*)(&Bs[row * LPP + kc * 8]) = vb;
        }
        __syncthreads();
        short8 af[4], bf4[4];
#pragma unroll
        for (int i = 0; i < 4; ++i)
            af[i] = *(const short8*)(&As[(wr * 64 + i * 16 + lrow) * LPP + kq * 8]);
#pragma unroll
        for (int jj = 0; jj < 4; ++jj)
            bf4[jj] = *(const short8*)(&Bs[(wc * 64 + jj * 16 + lrow) * LPP + kq * 8]);
#pragma unroll
        for (int i = 0; i < 4; ++i)
#pragma unroll
            for (int jj = 0; jj < 4; ++jj)
                acc[i][jj] = __builtin_amdgcn_mfma_f32_16x16x32_bf16(af[i], bf4[jj],
                                                                     acc[i][jj], 0, 0, 0);
        __syncthreads();
    }
    // C/D layout: row = quad*4 + reg, col = lane&15
    if (Cf) {
#pragma unroll
        for (int i = 0; i < 4; ++i)
#pragma unroll
            for (int jj = 0; jj < 4; ++jj) {
                int gn = n0 + wc * 64 + jj * 16 + lrow;
                float bsum = bias[gn] + bias2[gn];
#pragma unroll
                for (int reg = 0; reg < 4; ++reg) {
                    int gm = m0 + wr * 64 + i * 16 + kq * 4 + reg;
                    if (gm < M) Cf[(size_t)gm * 256 + gn] = acc[i][jj][reg] + bsum;
                }
            }
    } else {
#pragma unroll
        for (int i = 0; i < 4; ++i)
#pragma unroll
            for (int jj = 0; jj < 4; ++jj) {
                int gn = n0 + wc * 64 + jj * 16 + lrow;
#pragma unroll
                for (int reg = 0; reg < 4; ++reg) {
                    int gm = m0 + wr * 64 + i * 16 + kq * 4 + reg;
                    if (gm < M)
                        Cbf[((size_t)z * M + gm) * 256 + gn] = f2bf(acc[i][jj][reg]);
                }
            }
    }
}

// ---------------- message aggregation (CSR gather, unroll-2) ----------------
__global__ void k_msg_gather(const int* __restrict__ rowptr, const int* __restrict__ csr_se,
                             const float* __restrict__ alpha_csr,
                             const unsigned short* __restrict__ xw,
                             const float* __restrict__ bias, float* __restrict__ out,
                             unsigned short* __restrict__ xbout,
                             int r0, int r1, int first, int act) {
    int gid = blockIdx.x * blockDim.x + threadIdx.x;
    int node = gid >> 6, lane = gid & 63;
    if (node >= N) return;
    int hsel = lane >> 4;
    float ax = 0.f, ay = 0.f, az = 0.f, aw = 0.f;
    int beg = rowptr[node], end = rowptr[node + 1];
    int i = beg;
    for (; i + 2 <= end; i += 2) {
        int se0 = csr_se[i], se1 = csr_se[i + 1];
        int t0 = se0 >> 16, t1 = se1 >> 16;
        float a0 = alpha_csr[i * 4 + hsel];
        float a1v = alpha_csr[(i + 1) * 4 + hsel];
        if (t0 >= r0 && t0 < r1) {
            int s = se0 & 0xFFFF;
            uint2 p = *(const uint2*)(xw + ((size_t)(t0 - r0) * N + s) * 256 + lane * 4);
            ax += a0 * __uint_as_float(p.x << 16);
            ay += a0 * __uint_as_float(p.x & 0xFFFF0000u);
            az += a0 * __uint_as_float(p.y << 16);
            aw += a0 * __uint_as_float(p.y & 0xFFFF0000u);
        }
        if (t1 >= r0 && t1 < r1) {
            int s = se1 & 0xFFFF;
            uint2 p = *(const uint2*)(xw + ((size_t)(t1 - r0) * N + s) * 256 + lane * 4);
            ax += a1v * __uint_as_float(p.x << 16);
            ay += a1v * __uint_as_float(p.x & 0xFFFF0000u);
            az += a1v * __uint_as_float(p.y << 16);
            aw += a1v * __uint_as_float(p.y & 0xFFFF0000u);
        }
    }
    if (i < end) {
        int se = csr_se[i];
        int tt = se >> 16;
        if (tt >= r0 && tt < r1) {
            int s = se & 0xFFFF;
            float a = alpha_csr[i * 4 + hsel];
            uint2 p = *(const uint2*)(xw + ((size_t)(tt - r0) * N + s) * 256 + lane * 4);
            ax += a * __uint_as_float(p.x << 16);
            ay += a * __uint_as_float(p.x & 0xFFFF0000u);
            az += a * __uint_as_float(p.y << 16);
            aw += a * __uint_as_float(p.y & 0xFFFF0000u);
        }
    }
    float* o = out + (size_t)node * 256 + lane * 4;
    float vx, vy, vz, vw;
    if (first) {
        const float4 b = ((const float4*)bias)[lane];
        vx = ax + b.x; vy = ay + b.y; vz = az + b.z; vw = aw + b.w;
    } else {
        vx = o[0] + ax; vy = o[1] + ay; vz = o[2] + az; vw = o[3] + aw;
    }
    if (act) {
        vx = lrelu(vx, 0.01f); vy = lrelu(vy, 0.01f);
        vz = lrelu(vz, 0.01f); vw = lrelu(vw, 0.01f);
        unsigned short* xo = xbout + (size_t)node * 256 + lane * 4;
        xo[0] = f2bf(vx); xo[1] = f2bf(vy); xo[2] = f2bf(vz); xo[3] = f2bf(vw);
    }
    o[0] = vx; o[1] = vy; o[2] = vz; o[3] = vw;
}

extern "C" void kernel_launch(void* const* d_in, const int* in_sizes, int n_in,
                              void* d_out, int out_size, void* d_ws, size_t ws_size,
                              hipStream_t stream) {
    const float* kg   = (const float*)d_in[0];
    const float* cc0  = (const float*)d_in[1];
    const float* gw1  = (const float*)d_in[2];
    const float* gb1  = (const float*)d_in[3];
    const float* gw2  = (const float*)d_in[4];
    const float* gb2  = (const float*)d_in[5];
    const float* r1w  = (const float*)d_in[6];
    const float* r1q  = (const float*)d_in[7];
    const float* r1k  = (const float*)d_in[8];
    const float* r1b  = (const float*)d_in[9];
    const float* r2w  = (const float*)d_in[10];
    const float* r2q  = (const float*)d_in[11];
    const float* r2k  = (const float*)d_in[12];
    const float* r2b  = (const float*)d_in[13];
    const float* linw = (const float*)d_in[14];
    const float* linb = (const float*)d_in[15];
    const int*   ei   = (const int*)d_in[16];
    const int*   et   = (const int*)d_in[17];

    float* out = (float*)d_out;
    float* a1  = out + (size_t)N * C;
    float* a2  = a1 + (size_t)E * H;

    float* ws = (float*)d_ws;
    size_t off = 0;
    float* dis  = ws + off; off += N;
    float* h1   = ws + off; off += (size_t)N * 32;
    float* c1   = ws + off; off += (size_t)N * 32;
    unsigned short* h2b = (unsigned short*)(ws + off); off += (size_t)N * 64;
    float* x0   = ws + off; off += (size_t)N * C;
    float* hmid = ws + off; off += (size_t)N * C;
    float* qn   = ws + off; off += (size_t)N * R * H;
    float* kn   = ws + off; off += (size_t)N * R * H;
    int* cnt     = (int*)(ws + off); off += N;
    int* rowptr  = (int*)(ws + off); off += N + 1;
    int* cursor  = (int*)(ws + off); off += N;
    int* csr_se  = (int*)(ws + off); off += E;
    int* csr_eid = (int*)(ws + off); off += E;
    float* alpha = ws + off; off += (size_t)E * H;
    unsigned short* xb0 = (unsigned short*)(ws + off); off += (size_t)N * 128;
    unsigned short* xb1 = (unsigned short*)(ws + off); off += (size_t)N * 128;
    unsigned short* wt  = (unsigned short*)(ws + off); off += (size_t)R * 32768;
    unsigned short* wtl = (unsigned short*)(ws + off); off += 32768;
    unsigned short* wqkb = (unsigned short*)(ws + off); off += 8192;
    unsigned short* xwb = (unsigned short*)(ws + off);

    size_t fixedB = off * 4;
    int K = R;
    if (ws_size > fixedB) {
        size_t kmax = (ws_size - fixedB) / ((size_t)N * C * 2);
        if (kmax < (size_t)K) K = (int)kmax;
    } else {
        K = 1;
    }
    if (K < 1) K = 1;

    const int B = 256;
    auto cdiv = [](long a, long b) { return (int)((a + b - 1) / b); };
    const int MT = cdiv(N, TM);  // 157 m-tiles

    // ---- CSR build ----
    k_zero_int<<<cdiv(N, B), B, 0, stream>>>(cnt, N);
    k_count<<<cdiv(E, B), B, 0, stream>>>(ei, cnt);
    k_scan<<<1, 1024, 0, stream>>>(cnt, rowptr, cursor, dis);
    k_scatter<<<cdiv(E, B), B, 0, stream>>>(ei, et, cursor, csr_se, csr_eid);

    // ---- GCN ----
    k_h1<<<cdiv((long)N * 32, B), B, 0, stream>>>(cc0, gw1, h1);
    k_agg32<<<cdiv((long)N * 32, B), B, 0, stream>>>(rowptr, csr_se, dis, h1, gb1, c1);
    k_h2kg<<<cdiv((long)N * 128, B), B, 0, stream>>>(c1, gw2, kg, h2b, x0, xb0);
    k_agg128<<<cdiv((long)N * 128, B), B, 0, stream>>>(rowptr, csr_se, dis, h2b,
                                                       gb2, x0, xb0);

    auto rgat = [&](unsigned short* xb, const float* W,
                    const float* q, const float* kk, const float* b,
                    float* obuf, unsigned short* xbout, float* aout,
                    int first, int act) {
        k_wqkb<<<cdiv((long)64 * 256, B), B, 0, stream>>>(W, q, kk, wqkb);
        k_qnkn_mfma<<<cdiv(N, 64), B, 0, stream>>>(xb, wqkb, qn, kn);
        k_soft<<<cdiv((long)N * 64, B), B, 0, stream>>>(rowptr, csr_se, csr_eid,
                                                        qn, kn, alpha, aout);
        k_wconv_t<<<R * 16, 256, 0, stream>>>(W, wt);
        for (int r0 = 0; r0 < R; r0 += K) {
            int kc = (R - r0) < K ? (R - r0) : K;
            int gx = 8 * kc * (C / TN) * cdiv(MT, 8);
            gemm_mfma3<<<gx, 256, 0, stream>>>(xb, wt + ((size_t)r0 << 16), xwb,
                                               nullptr, nullptr, nullptr,
                                               N, kc, C / TN, MT);
            int last = (r0 + kc >= R) ? 1 : 0;
            k_msg_gather<<<cdiv((long)N * 64, B), B, 0, stream>>>(
                rowptr, csr_se, alpha, xwb, b, obuf, xbout, r0, r0 + kc,
                (first && r0 == 0) ? 1 : 0, act && last);
        }
    };

    // layer 1: hmid = bias + messages, leaky fused, emits xb1 bf16
    rgat(xb0, r1w, r1q, r1k, r1b, hmid, xb1, a1, 1, 1);

    // residual linear BEFORE layer-2 messages: out = x0@linw + (linb + r2b)
    k_wconv_t<<<16, 256, 0, stream>>>(linw, wtl);
    {
        int gx = 8 * 1 * (C / TN) * cdiv(MT, 8);
        gemm_mfma3<<<gx, 256, 0, stream>>>(xb0, wtl, nullptr, out, linb, r2b,
                                           N, 1, C / TN, MT);
    }

    // layer 2: out += messages (bias already folded into linear epilogue)
    rgat(xb1, r2w, r2q, r2k, r2b, out, nullptr, a2, 0, 0);
}

// Round 11
// 539.198 us; speedup vs baseline: 1.1733x; 1.0400x over previous
//
#include <hip/hip_runtime.h>
#include <cstdint>

static constexpr int N = 20000;
static constexpr int E = 320000;
static constexpr int R = 8;
static constexpr int H = 4;
static constexpr int C = 256;

using short8 = __attribute__((ext_vector_type(8))) short;
using f32x4  = __attribute__((ext_vector_type(4))) float;

__device__ __forceinline__ float lrelu(float x, float s) { return x >= 0.f ? x : s * x; }
__device__ __forceinline__ unsigned short f2bf(float f) {
    unsigned u = __float_as_uint(f);
    unsigned r = (u + 0x7FFFu + ((u >> 16) & 1u)) >> 16;
    return (unsigned short)r;
}
__device__ __forceinline__ float bf2f(unsigned short s) {
    return __uint_as_float(((unsigned)s) << 16);
}

// ---------------- CSR build ----------------
__global__ void k_zero_int(int* p, int n) {
    int i = blockIdx.x * blockDim.x + threadIdx.x;
    if (i < n) p[i] = 0;
}

__global__ void k_count(const int* __restrict__ ei, int* __restrict__ cnt) {
    int e = blockIdx.x * blockDim.x + threadIdx.x;
    if (e < E) atomicAdd(&cnt[ei[E + e]], 1);
}

// exclusive scan of cnt -> rowptr; also emits cursor copy and dis = rsqrt(cnt+1)
__global__ __launch_bounds__(1024) void k_scan(const int* __restrict__ cnt,
                                               int* __restrict__ rowptr,
                                               int* __restrict__ cursor,
                                               float* __restrict__ dis) {
    __shared__ int part[1024];
    const int CH = (N + 1023) / 1024;  // 20
    int t = threadIdx.x;
    int base = t * CH;
    int sum = 0;
    for (int j = 0; j < CH; ++j) {
        int idx = base + j;
        if (idx < N) sum += cnt[idx];
    }
    part[t] = sum;
    __syncthreads();
    for (int off = 1; off < 1024; off <<= 1) {
        int v = 0;
        if (t >= off) v = part[t - off];
        __syncthreads();
        if (t >= off) part[t] += v;
        __syncthreads();
    }
    int run = part[t] - sum;
    for (int j = 0; j < CH; ++j) {
        int idx = base + j;
        if (idx < N) {
            int cv = cnt[idx];
            rowptr[idx] = run;
            cursor[idx] = run;
            dis[idx] = rsqrtf((float)cv + 1.0f);
            run += cv;
        }
    }
    if (t == 1023) rowptr[N] = part[1023];
}

// csr_se packs (edge_type<<16)|src ; csr_eid keeps original edge id
__global__ void k_scatter(const int* __restrict__ ei, const int* __restrict__ et,
                          int* __restrict__ cursor, int* __restrict__ csr_se,
                          int* __restrict__ csr_eid) {
    int e = blockIdx.x * blockDim.x + threadIdx.x;
    if (e >= E) return;
    int d = ei[E + e];
    int pos = atomicAdd(&cursor[d], 1);
    csr_se[pos] = (et[e] << 16) | ei[e];
    csr_eid[pos] = e;
}

// ---------------- GCN ----------------
__global__ void k_h1(const float* __restrict__ x, const float* __restrict__ W,
                     float* __restrict__ h) {
    int idx = blockIdx.x * blockDim.x + threadIdx.x;
    if (idx >= N * 32) return;
    int n = idx >> 5, f = idx & 31;
    const float* xr = x + n * 4;
    float acc = 0.f;
#pragma unroll
    for (int c = 0; c < 4; ++c) acc += xr[c] * W[c * 32 + f];
    h[idx] = acc;
}

__global__ void k_agg32(const int* __restrict__ rowptr, const int* __restrict__ csr_se,
                        const float* __restrict__ dis, const float* __restrict__ h,
                        const float* __restrict__ b, float* __restrict__ c) {
    int idx = blockIdx.x * blockDim.x + threadIdx.x;
    if (idx >= N * 32) return;
    int d = idx >> 5, f = idx & 31;
    int beg = rowptr[d], end = rowptr[d + 1];
    float acc = 0.f;
    for (int i = beg; i < end; ++i) {
        int s = csr_se[i] & 0xFFFF;
        acc += dis[s] * h[s * 32 + f];
    }
    float dd = dis[d];
    c[idx] = dd * acc + dd * dd * h[idx] + b[f];
}

// h2 (bf16) + kg copy into x0/xb0, one dispatch
__global__ void k_h2kg(const float* __restrict__ c1, const float* __restrict__ W,
                       const float* __restrict__ kg, unsigned short* __restrict__ h,
                       float* __restrict__ x0, unsigned short* __restrict__ xb0) {
    int idx = blockIdx.x * blockDim.x + threadIdx.x;
    if (idx >= N * 128) return;
    int n = idx >> 7, f = idx & 127;
    const float* cr = c1 + n * 32;
    float acc = 0.f;
    for (int c = 0; c < 32; ++c) acc += lrelu(cr[c], 0.01f) * W[c * 128 + f];
    h[idx] = f2bf(acc);
    float v = kg[idx];
    x0[n * 256 + f] = v;
    xb0[n * 256 + f] = f2bf(v);
}

__global__ void k_agg128(const int* __restrict__ rowptr, const int* __restrict__ csr_se,
                         const float* __restrict__ dis,
                         const unsigned short* __restrict__ h,
                         const float* __restrict__ b, float* __restrict__ x0,
                         unsigned short* __restrict__ xb0) {
    int idx = blockIdx.x * blockDim.x + threadIdx.x;
    if (idx >= N * 128) return;
    int d = idx >> 7, f = idx & 127;
    int beg = rowptr[d], end = rowptr[d + 1];
    float acc = 0.f;
    int i = beg;
    for (; i + 2 <= end; i += 2) {
        int s0 = csr_se[i] & 0xFFFF;
        int s1 = csr_se[i + 1] & 0xFFFF;
        float d0 = dis[s0], d1 = dis[s1];
        float v0 = bf2f(h[s0 * 128 + f]), v1 = bf2f(h[s1 * 128 + f]);
        acc += d0 * v0 + d1 * v1;
    }
    if (i < end) {
        int s = csr_se[i] & 0xFFFF;
        acc += dis[s] * bf2f(h[s * 128 + f]);
    }
    float dd = dis[d];
    float v = dd * acc + dd * dd * bf2f(h[d * 128 + f]) + b[f];
    x0[d * 256 + 128 + f] = v;
    xb0[d * 256 + 128 + f] = f2bf(v);
}

// ---------------- RGAT attention ----------------
// fused W@q / W@k projection, written directly as bf16 [n][k] (n<32: q, else k)
__global__ void k_wqkb(const float* __restrict__ W, const float* __restrict__ q,
                       const float* __restrict__ kmat, unsigned short* __restrict__ wqkb) {
    int idx = blockIdx.x * blockDim.x + threadIdx.x;
    if (idx >= 64 * 256) return;
    int n = idx >> 8, i = idx & 255;
    int m = n & 31;
    int r = m >> 2, h = m & 3;
    const float* src = (n < 32) ? q : kmat;
    const float* wr = W + ((long)r * 256 + i) * 256;
    float acc = 0.f;
    for (int o = 0; o < 256; ++o) acc += wr[o] * src[o * 4 + h];
    wqkb[n * 256 + i] = f2bf(acc);
}

// qn|kn = xb @ wqkb^T via MFMA.  Block: 256 thr = 4 waves, 64 rows per block.
#define QP 264
__global__ __launch_bounds__(256) void k_qnkn_mfma(
    const unsigned short* __restrict__ xb, const unsigned short* __restrict__ wqkb,
    float* __restrict__ qn, float* __restrict__ kn)
{
    __shared__ unsigned short Ws[64 * QP];
    int t = threadIdx.x;
    {
        int r = t >> 2, off = (t & 3) * 64;
#pragma unroll
        for (int i = 0; i < 8; ++i)
            *(uint4*)(&Ws[r * QP + off + i * 8]) =
                *(const uint4*)(wqkb + r * 256 + off + i * 8);
    }
    __syncthreads();
    int wave = t >> 6, lane = t & 63;
    int lrow = lane & 15, kq = lane >> 4;
    int mw = blockIdx.x * 64 + wave * 16;
    int gm = mw + lrow;
    int gmc = gm < N ? gm : N - 1;

    f32x4 acc[4];
#pragma unroll
    for (int j = 0; j < 4; ++j) acc[j] = (f32x4){0.f, 0.f, 0.f, 0.f};

    for (int k0 = 0; k0 < 8; ++k0) {
        short8 af = *(const short8*)(xb + (size_t)gmc * 256 + k0 * 32 + kq * 8);
#pragma unroll
        for (int j = 0; j < 4; ++j) {
            short8 bf4 = *(const short8*)(&Ws[(j * 16 + lrow) * QP + k0 * 32 + kq * 8]);
            acc[j] = __builtin_amdgcn_mfma_f32_16x16x32_bf16(af, bf4, acc[j], 0, 0, 0);
        }
    }
#pragma unroll
    for (int j = 0; j < 4; ++j) {
        int col = j * 16 + lrow;
#pragma unroll
        for (int reg = 0; reg < 4; ++reg) {
            int gr = mw + kq * 4 + reg;
            if (gr < N) {
                if (col < 32) qn[gr * 32 + col] = acc[j][reg];
                else          kn[gr * 32 + (col - 32)] = acc[j][reg];
            }
        }
    }
}

// wave-per-node softmax: lanes = 16 edge-slots x 4 heads, shuffle reductions.
__global__ void k_soft(const int* __restrict__ rowptr, const int* __restrict__ csr_se,
                       const int* __restrict__ csr_eid,
                       const float* __restrict__ qn, const float* __restrict__ kn,
                       float* __restrict__ alpha_csr, float* __restrict__ aout) {
    int wid = (blockIdx.x * blockDim.x + threadIdx.x) >> 6;
    int lane = threadIdx.x & 63;
    if (wid >= N) return;
    int d = wid;
    int beg = rowptr[d], end = rowptr[d + 1];
    if (beg >= end) return;
    int slot = lane >> 2, h = lane & 3;
    int nc = (end - beg + 15) >> 4;
    const float* qrow = qn + d * 32;

    auto rawv = [&](int i) {
        int se = csr_se[i];
        int tt = se >> 16, s = se & 0xFFFF;
        return lrelu(qrow[tt * 4 + h] + kn[s * 32 + tt * 4 + h], 0.2f);
    };

    float av[4];
    float m = -1e30f;
    for (int c = 0; c < nc; ++c) {
        int i = beg + c * 16 + slot;
        float v = (i < end) ? rawv(i) : -1e30f;
        if (c < 4) av[c] = v;
        m = fmaxf(m, v);
    }
    m = fmaxf(m, __shfl_xor(m, 4));
    m = fmaxf(m, __shfl_xor(m, 8));
    m = fmaxf(m, __shfl_xor(m, 16));
    m = fmaxf(m, __shfl_xor(m, 32));

    float sum = 0.f;
    for (int c = 0; c < nc; ++c) {
        int i = beg + c * 16 + slot;
        float ex = 0.f;
        if (i < end) {
            float v = (c < 4) ? av[c] : rawv(i);
            ex = expf(v - m);
        }
        if (c < 4) av[c] = ex;
        sum += ex;
    }
    sum += __shfl_xor(sum, 4);
    sum += __shfl_xor(sum, 8);
    sum += __shfl_xor(sum, 16);
    sum += __shfl_xor(sum, 32);
    float inv = 1.f / sum;

    for (int c = 0; c < nc; ++c) {
        int i = beg + c * 16 + slot;
        if (i < end) {
            float ex = (c < 4) ? av[c] : expf(rawv(i) - m);
            float a = ex * inv;
            alpha_csr[i * 4 + h] = a;
            aout[csr_eid[i] * 4 + h] = a;
        }
    }
}

// Wt[z][n][k] = bf16(W[z][k][n])  -- 64x64 LDS-tile transpose, coalesced both ways
#define WTP 72
__global__ __launch_bounds__(256) void k_wconv_t(const float* __restrict__ W,
                                                 unsigned short* __restrict__ Wt) {
    int bid = blockIdx.x;
    int z = bid >> 4;
    int tile = bid & 15;
    int k0 = (tile >> 2) * 64, n0 = (tile & 3) * 64;
    __shared__ unsigned short T[64 * WTP];
    int t = threadIdx.x;
    const float* Wz = W + ((size_t)z << 16);
    int r = t >> 4;
    int cs = (t & 15) * 4;
#pragma unroll
    for (int rr = 0; rr < 4; ++rr) {
        int k = r + rr * 16;
        float4 v = *(const float4*)(Wz + (size_t)(k0 + k) * 256 + n0 + cs);
        T[(cs + 0) * WTP + k] = f2bf(v.x);
        T[(cs + 1) * WTP + k] = f2bf(v.y);
        T[(cs + 2) * WTP + k] = f2bf(v.z);
        T[(cs + 3) * WTP + k] = f2bf(v.w);
    }
    __syncthreads();
    int n = t >> 2, ck = (t & 3) * 16;
    unsigned short* dst = Wt + ((size_t)z << 16) + (size_t)(n0 + n) * 256 + k0 + ck;
    const unsigned short* srcp = T + n * WTP + ck;
    *(uint4*)(dst) = *(const uint4*)(srcp);
    *(uint4*)(dst + 8) = *(const uint4*)(srcp + 8);
}

// ---------------- bf16 MFMA GEMM: 512 thr, 8 waves of 64x32, XCD-swizzled ------
// z < zlin (or zlin<0): Cbf[z][M][256] = bf16(A@B[z])
// z == zlin          : Cf = A@B[z] + bias + bias2   (fp32, full store)
#define TM 128
#define TN 128
#define TK 32
#define LPP 40
__global__ __launch_bounds__(512) void gemm_mfma4(
    const unsigned short* __restrict__ A, const unsigned short* __restrict__ Bt,
    unsigned short* __restrict__ Cbf, float* __restrict__ Cf,
    const float* __restrict__ bias, const float* __restrict__ bias2,
    int M, int NZ, int NT, int MT, int zlin)
{
    __shared__ unsigned short As[TM * LPP];
    __shared__ unsigned short Bs[TN * LPP];

    int bi = blockIdx.x;
    int cx = bi & 7;
    int g = bi >> 3;
    int per = NZ * NT;
    int mh = g / per;
    int j  = g % per;
    int mt = mh * 8 + cx;
    if (mt >= MT) return;
    int z  = j % NZ;
    int nb = j / NZ;
    int m0 = mt * TM;
    int n0 = nb * TN;

    const unsigned short* Bz = Bt + ((size_t)z << 16);
    int t = threadIdx.x;
    int wave = t >> 6, lane = t & 63;
    int wr = wave >> 2;      // 0..1 : 64-row half
    int wc = wave & 3;       // 0..3 : 32-col block
    int lrow = lane & 15, kq = lane >> 4;
    int srow = t >> 2, skc = t & 3;

    f32x4 acc[4][2];
#pragma unroll
    for (int i = 0; i < 4; ++i)
#pragma unroll
        for (int jj = 0; jj < 2; ++jj) acc[i][jj] = (f32x4){0.f, 0.f, 0.f, 0.f};

    for (int k0 = 0; k0 < 256; k0 += TK) {
        {
            int gm = m0 + srow;
            uint4 va = {0, 0, 0, 0};
            if (gm < M) va = *(const uint4*)(A + (size_t)gm * 256 + k0 + skc * 8);
            *(uint4*)(&As[srow * LPP + skc * 8]) = va;
            uint4 vb = *(const uint4*)(Bz + (size_t)(n0 + srow) * 256 + k0 + skc * 8);
            *(uint4*)(&Bs[srow * LPP + skc * 8]) = vb;
        }
        __syncthreads();
        short8 af[4], bf4[2];
#pragma unroll
        for (int i = 0; i < 4; ++i)
            af[i] = *(const short8*)(&As[(wr * 64 + i * 16 + lrow) * LPP + kq * 8]);
#pragma unroll
        for (int jj = 0; jj < 2; ++jj)
            bf4[jj] = *(const short8*)(&Bs[(wc * 32 + jj * 16 + lrow) * LPP + kq * 8]);
#pragma unroll
        for (int i = 0; i < 4; ++i)
#pragma unroll
            for (int jj = 0; jj < 2; ++jj)
                acc[i][jj] = __builtin_amdgcn_mfma_f32_16x16x32_bf16(af[i], bf4[jj],
                                                                     acc[i][jj], 0, 0, 0);
        __syncthreads();
    }
    // C/D layout: row = quad*4 + reg, col = lane&15
    if (z == zlin) {
#pragma unroll
        for (int i = 0; i < 4; ++i)
#pragma unroll
            for (int jj = 0; jj < 2; ++jj) {
                int gn = n0 + wc * 32 + jj * 16 + lrow;
                float bsum = bias[gn] + bias2[gn];
#pragma unroll
                for (int reg = 0; reg < 4; ++reg) {
                    int gm = m0 + wr * 64 + i * 16 + kq * 4 + reg;
                    if (gm < M) Cf[(size_t)gm * 256 + gn] = acc[i][jj][reg] + bsum;
                }
            }
    } else {
#pragma unroll
        for (int i = 0; i < 4; ++i)
#pragma unroll
            for (int jj = 0; jj < 2; ++jj) {
                int gn = n0 + wc * 32 + jj * 16 + lrow;
#pragma unroll
                for (int reg = 0; reg < 4; ++reg) {
                    int gm = m0 + wr * 64 + i * 16 + kq * 4 + reg;
                    if (gm < M)
                        Cbf[((size_t)z * M + gm) * 256 + gn] = f2bf(acc[i][jj][reg]);
                }
            }
    }
}

// ---------------- message aggregation (CSR gather, unroll-2) ----------------
__global__ void k_msg_gather(const int* __restrict__ rowptr, const int* __restrict__ csr_se,
                             const float* __restrict__ alpha_csr,
                             const unsigned short* __restrict__ xw,
                             const float* __restrict__ bias, float* __restrict__ out,
                             unsigned short* __restrict__ xbout,
                             int r0, int r1, int first, int act) {
    int gid = blockIdx.x * blockDim.x + threadIdx.x;
    int node = gid >> 6, lane = gid & 63;
    if (node >= N) return;
    int hsel = lane >> 4;
    float ax = 0.f, ay = 0.f, az = 0.f, aw = 0.f;
    int beg = rowptr[node], end = rowptr[node + 1];
    int i = beg;
    for (; i + 2 <= end; i += 2) {
        int se0 = csr_se[i], se1 = csr_se[i + 1];
        int t0 = se0 >> 16, t1 = se1 >> 16;
        float a0 = alpha_csr[i * 4 + hsel];
        float a1v = alpha_csr[(i + 1) * 4 + hsel];
        if (t0 >= r0 && t0 < r1) {
            int s = se0 & 0xFFFF;
            uint2 p = *(const uint2*)(xw + ((size_t)(t0 - r0) * N + s) * 256 + lane * 4);
            ax += a0 * __uint_as_float(p.x << 16);
            ay += a0 * __uint_as_float(p.x & 0xFFFF0000u);
            az += a0 * __uint_as_float(p.y << 16);
            aw += a0 * __uint_as_float(p.y & 0xFFFF0000u);
        }
        if (t1 >= r0 && t1 < r1) {
            int s = se1 & 0xFFFF;
            uint2 p = *(const uint2*)(xw + ((size_t)(t1 - r0) * N + s) * 256 + lane * 4);
            ax += a1v * __uint_as_float(p.x << 16);
            ay += a1v * __uint_as_float(p.x & 0xFFFF0000u);
            az += a1v * __uint_as_float(p.y << 16);
            aw += a1v * __uint_as_float(p.y & 0xFFFF0000u);
        }
    }
    if (i < end) {
        int se = csr_se[i];
        int tt = se >> 16;
        if (tt >= r0 && tt < r1) {
            int s = se & 0xFFFF;
            float a = alpha_csr[i * 4 + hsel];
            uint2 p = *(const uint2*)(xw + ((size_t)(tt - r0) * N + s) * 256 + lane * 4);
            ax += a * __uint_as_float(p.x << 16);
            ay += a * __uint_as_float(p.x & 0xFFFF0000u);
            az += a * __uint_as_float(p.y << 16);
            aw += a * __uint_as_float(p.y & 0xFFFF0000u);
        }
    }
    float* o = out + (size_t)node * 256 + lane * 4;
    float vx, vy, vz, vw;
    if (first) {
        const float4 b = ((const float4*)bias)[lane];
        vx = ax + b.x; vy = ay + b.y; vz = az + b.z; vw = aw + b.w;
    } else {
        vx = o[0] + ax; vy = o[1] + ay; vz = o[2] + az; vw = o[3] + aw;
    }
    if (act) {
        vx = lrelu(vx, 0.01f); vy = lrelu(vy, 0.01f);
        vz = lrelu(vz, 0.01f); vw = lrelu(vw, 0.01f);
        unsigned short* xo = xbout + (size_t)node * 256 + lane * 4;
        xo[0] = f2bf(vx); xo[1] = f2bf(vy); xo[2] = f2bf(vz); xo[3] = f2bf(vw);
    }
    o[0] = vx; o[1] = vy; o[2] = vz; o[3] = vw;
}

extern "C" void kernel_launch(void* const* d_in, const int* in_sizes, int n_in,
                              void* d_out, int out_size, void* d_ws, size_t ws_size,
                              hipStream_t stream) {
    const float* kg   = (const float*)d_in[0];
    const float* cc0  = (const float*)d_in[1];
    const float* gw1  = (const float*)d_in[2];
    const float* gb1  = (const float*)d_in[3];
    const float* gw2  = (const float*)d_in[4];
    const float* gb2  = (const float*)d_in[5];
    const float* r1w  = (const float*)d_in[6];
    const float* r1q  = (const float*)d_in[7];
    const float* r1k  = (const float*)d_in[8];
    const float* r1b  = (const float*)d_in[9];
    const float* r2w  = (const float*)d_in[10];
    const float* r2q  = (const float*)d_in[11];
    const float* r2k  = (const float*)d_in[12];
    const float* r2b  = (const float*)d_in[13];
    const float* linw = (const float*)d_in[14];
    const float* linb = (const float*)d_in[15];
    const int*   ei   = (const int*)d_in[16];
    const int*   et   = (const int*)d_in[17];

    float* out = (float*)d_out;
    float* a1  = out + (size_t)N * C;
    float* a2  = a1 + (size_t)E * H;

    float* ws = (float*)d_ws;
    size_t off = 0;
    float* dis  = ws + off; off += N;
    float* h1   = ws + off; off += (size_t)N * 32;
    float* c1   = ws + off; off += (size_t)N * 32;
    unsigned short* h2b = (unsigned short*)(ws + off); off += (size_t)N * 64;
    float* x0   = ws + off; off += (size_t)N * C;
    float* hmid = ws + off; off += (size_t)N * C;
    float* qn   = ws + off; off += (size_t)N * R * H;
    float* kn   = ws + off; off += (size_t)N * R * H;
    int* cnt     = (int*)(ws + off); off += N;
    int* rowptr  = (int*)(ws + off); off += N + 1;
    int* cursor  = (int*)(ws + off); off += N;
    int* csr_se  = (int*)(ws + off); off += E;
    int* csr_eid = (int*)(ws + off); off += E;
    float* alpha = ws + off; off += (size_t)E * H;
    unsigned short* xb0 = (unsigned short*)(ws + off); off += (size_t)N * 128;
    unsigned short* xb1 = (unsigned short*)(ws + off); off += (size_t)N * 128;
    // wt[0..R-1] = RGAT weights (transposed bf16); wt[R] = lin weight -> contiguous
    unsigned short* wt  = (unsigned short*)(ws + off); off += (size_t)(R + 1) * 32768;
    unsigned short* wtl = wt + ((size_t)R << 16);
    unsigned short* wqkb = (unsigned short*)(ws + off); off += 8192;
    unsigned short* xwb = (unsigned short*)(ws + off);

    size_t fixedB = off * 4;
    int K = R;
    if (ws_size > fixedB) {
        size_t kmax = (ws_size - fixedB) / ((size_t)N * C * 2);
        if (kmax < (size_t)K) K = (int)kmax;
    } else {
        K = 1;
    }
    if (K < 1) K = 1;

    const int B = 256;
    auto cdiv = [](long a, long b) { return (int)((a + b - 1) / b); };
    const int MT = cdiv(N, TM);  // 157 m-tiles
    const int NT = C / TN;       // 1... (C=256,TN=128 -> 2)

    // ---- CSR build ----
    k_zero_int<<<cdiv(N, B), B, 0, stream>>>(cnt, N);
    k_count<<<cdiv(E, B), B, 0, stream>>>(ei, cnt);
    k_scan<<<1, 1024, 0, stream>>>(cnt, rowptr, cursor, dis);
    k_scatter<<<cdiv(E, B), B, 0, stream>>>(ei, et, cursor, csr_se, csr_eid);

    // ---- GCN ----
    k_h1<<<cdiv((long)N * 32, B), B, 0, stream>>>(cc0, gw1, h1);
    k_agg32<<<cdiv((long)N * 32, B), B, 0, stream>>>(rowptr, csr_se, dis, h1, gb1, c1);
    k_h2kg<<<cdiv((long)N * 128, B), B, 0, stream>>>(c1, gw2, kg, h2b, x0, xb0);
    k_agg128<<<cdiv((long)N * 128, B), B, 0, stream>>>(rowptr, csr_se, dis, h2b,
                                                       gb2, x0, xb0);

    // lin: if nonzero, the last GEMM chunk appends z=kc computing
    //      linout = A@wt[R] + lb1 + lb2 (fp32)
    auto rgat = [&](unsigned short* xb, const float* W,
                    const float* q, const float* kk, const float* b,
                    float* obuf, unsigned short* xbout, float* aout,
                    int first, int act, int lin, float* linout,
                    const float* lb1, const float* lb2) {
        k_wqkb<<<cdiv((long)64 * 256, B), B, 0, stream>>>(W, q, kk, wqkb);
        k_qnkn_mfma<<<cdiv(N, 64), B, 0, stream>>>(xb, wqkb, qn, kn);
        k_soft<<<cdiv((long)N * 64, B), B, 0, stream>>>(rowptr, csr_se, csr_eid,
                                                        qn, kn, alpha, aout);
        k_wconv_t<<<R * 16, 256, 0, stream>>>(W, wt);
        for (int r0 = 0; r0 < R; r0 += K) {
            int kc = (R - r0) < K ? (R - r0) : K;
            int addlin = (lin && (r0 + kc == R)) ? 1 : 0;
            int nz = kc + addlin;
            int zl = addlin ? kc : -1;
            int gx = 8 * nz * NT * cdiv(MT, 8);
            gemm_mfma4<<<gx, 512, 0, stream>>>(xb, wt + ((size_t)r0 << 16), xwb,
                                               linout, lb1, lb2,
                                               N, nz, NT, MT, zl);
            int last = (r0 + kc >= R) ? 1 : 0;
            k_msg_gather<<<cdiv((long)N * 64, B), B, 0, stream>>>(
                rowptr, csr_se, alpha, xwb, b, obuf, xbout, r0, r0 + kc,
                (first && r0 == 0) ? 1 : 0, act && last);
        }
    };

    // residual-linear weight transposed into wt[R] before layer 1
    k_wconv_t<<<16, 256, 0, stream>>>(linw, wtl);

    // layer 1: hmid = r1b + messages (leaky fused, emits xb1 bf16);
    //          merged z=8 slice writes out = x0@linw + (linb + r2b)
    rgat(xb0, r1w, r1q, r1k, r1b, hmid, xb1, a1, 1, 1,
         1, out, linb, r2b);

    // layer 2: out += messages (bias already folded into linear epilogue)
    rgat(xb1, r2w, r2q, r2k, r2b, out, nullptr, a2, 0, 0,
         0, nullptr, nullptr, nullptr);
}

// Round 12
// 532.395 us; speedup vs baseline: 1.1883x; 1.0128x over previous
//
#include <hip/hip_runtime.h>
#include <cstdint>

static constexpr int N = 20000;
static constexpr int E = 320000;
static constexpr int R = 8;
static constexpr int H = 4;
static constexpr int C = 256;

using short8 = __attribute__((ext_vector_type(8))) short;
using f32x4  = __attribute__((ext_vector_type(4))) float;

__device__ __forceinline__ float lrelu(float x, float s) { return x >= 0.f ? x : s * x; }
__device__ __forceinline__ unsigned short f2bf(float f) {
    unsigned u = __float_as_uint(f);
    unsigned r = (u + 0x7FFFu + ((u >> 16) & 1u)) >> 16;
    return (unsigned short)r;
}
__device__ __forceinline__ float bf2f(unsigned short s) {
    return __uint_as_float(((unsigned)s) << 16);
}

// ---------------- CSR build ----------------
__global__ void k_zero_int(int* p, int n) {
    int i = blockIdx.x * blockDim.x + threadIdx.x;
    if (i < n) p[i] = 0;
}

__global__ void k_count(const int* __restrict__ ei, int* __restrict__ cnt) {
    int e = blockIdx.x * blockDim.x + threadIdx.x;
    if (e < E) atomicAdd(&cnt[ei[E + e]], 1);
}

// exclusive scan of cnt -> rowptr; also emits cursor copy and dis = rsqrt(cnt+1)
__global__ __launch_bounds__(1024) void k_scan(const int* __restrict__ cnt,
                                               int* __restrict__ rowptr,
                                               int* __restrict__ cursor,
                                               float* __restrict__ dis) {
    __shared__ int part[1024];
    const int CH = (N + 1023) / 1024;  // 20
    int t = threadIdx.x;
    int base = t * CH;
    int sum = 0;
    for (int j = 0; j < CH; ++j) {
        int idx = base + j;
        if (idx < N) sum += cnt[idx];
    }
    part[t] = sum;
    __syncthreads();
    for (int off = 1; off < 1024; off <<= 1) {
        int v = 0;
        if (t >= off) v = part[t - off];
        __syncthreads();
        if (t >= off) part[t] += v;
        __syncthreads();
    }
    int run = part[t] - sum;
    for (int j = 0; j < CH; ++j) {
        int idx = base + j;
        if (idx < N) {
            int cv = cnt[idx];
            rowptr[idx] = run;
            cursor[idx] = run;
            dis[idx] = rsqrtf((float)cv + 1.0f);
            run += cv;
        }
    }
    if (t == 1023) rowptr[N] = part[1023];
}

// csr_se packs (edge_type<<16)|src ; csr_eid keeps original edge id
__global__ void k_scatter(const int* __restrict__ ei, const int* __restrict__ et,
                          int* __restrict__ cursor, int* __restrict__ csr_se,
                          int* __restrict__ csr_eid) {
    int e = blockIdx.x * blockDim.x + threadIdx.x;
    if (e >= E) return;
    int d = ei[E + e];
    int pos = atomicAdd(&cursor[d], 1);
    csr_se[pos] = (et[e] << 16) | ei[e];
    csr_eid[pos] = e;
}

// ---------------- GCN ----------------
__global__ void k_h1(const float* __restrict__ x, const float* __restrict__ W,
                     float* __restrict__ h) {
    int idx = blockIdx.x * blockDim.x + threadIdx.x;
    if (idx >= N * 32) return;
    int n = idx >> 5, f = idx & 31;
    const float* xr = x + n * 4;
    float acc = 0.f;
#pragma unroll
    for (int c = 0; c < 4; ++c) acc += xr[c] * W[c * 32 + f];
    h[idx] = acc;
}

__global__ void k_agg32(const int* __restrict__ rowptr, const int* __restrict__ csr_se,
                        const float* __restrict__ dis, const float* __restrict__ h,
                        const float* __restrict__ b, float* __restrict__ c) {
    int idx = blockIdx.x * blockDim.x + threadIdx.x;
    if (idx >= N * 32) return;
    int d = idx >> 5, f = idx & 31;
    int beg = rowptr[d], end = rowptr[d + 1];
    float acc = 0.f;
    for (int i = beg; i < end; ++i) {
        int s = csr_se[i] & 0xFFFF;
        acc += dis[s] * h[s * 32 + f];
    }
    float dd = dis[d];
    c[idx] = dd * acc + dd * dd * h[idx] + b[f];
}

// h2 (bf16) + kg copy into x0/xb0, one dispatch
__global__ void k_h2kg(const float* __restrict__ c1, const float* __restrict__ W,
                       const float* __restrict__ kg, unsigned short* __restrict__ h,
                       float* __restrict__ x0, unsigned short* __restrict__ xb0) {
    int idx = blockIdx.x * blockDim.x + threadIdx.x;
    if (idx >= N * 128) return;
    int n = idx >> 7, f = idx & 127;
    const float* cr = c1 + n * 32;
    float acc = 0.f;
    for (int c = 0; c < 32; ++c) acc += lrelu(cr[c], 0.01f) * W[c * 128 + f];
    h[idx] = f2bf(acc);
    float v = kg[idx];
    x0[n * 256 + f] = v;
    xb0[n * 256 + f] = f2bf(v);
}

__global__ void k_agg128(const int* __restrict__ rowptr, const int* __restrict__ csr_se,
                         const float* __restrict__ dis,
                         const unsigned short* __restrict__ h,
                         const float* __restrict__ b, float* __restrict__ x0,
                         unsigned short* __restrict__ xb0) {
    int idx = blockIdx.x * blockDim.x + threadIdx.x;
    if (idx >= N * 128) return;
    int d = idx >> 7, f = idx & 127;
    int beg = rowptr[d], end = rowptr[d + 1];
    float acc = 0.f;
    int i = beg;
    for (; i + 2 <= end; i += 2) {
        int s0 = csr_se[i] & 0xFFFF;
        int s1 = csr_se[i + 1] & 0xFFFF;
        float d0 = dis[s0], d1 = dis[s1];
        float v0 = bf2f(h[s0 * 128 + f]), v1 = bf2f(h[s1 * 128 + f]);
        acc += d0 * v0 + d1 * v1;
    }
    if (i < end) {
        int s = csr_se[i] & 0xFFFF;
        acc += dis[s] * bf2f(h[s * 128 + f]);
    }
    float dd = dis[d];
    float v = dd * acc + dd * dd * bf2f(h[d * 128 + f]) + b[f];
    x0[d * 256 + 128 + f] = v;
    xb0[d * 256 + 128 + f] = f2bf(v);
}

// ---------------- RGAT attention ----------------
// wave-per-(r,i) W@q / W@k projection: coalesced row read + shuffle reduce.
// wqkb[n][k]: n<32 -> q proj (n = r*4+h), n>=32 -> k proj (n = 32+r*4+h)
__global__ __launch_bounds__(256) void k_wqkb(const float* __restrict__ W,
                                              const float* __restrict__ q,
                                              const float* __restrict__ kmat,
                                              unsigned short* __restrict__ wqkb) {
    int w = (blockIdx.x * blockDim.x + threadIdx.x) >> 6;  // 0..2047
    int lane = threadIdx.x & 63;
    int r = w >> 8, i = w & 255;
    const float* wr = W + ((size_t)(r * 256 + i)) * 256;
    float4 a = *(const float4*)(wr + lane * 4);
    float aq0 = 0.f, aq1 = 0.f, aq2 = 0.f, aq3 = 0.f;
    float ak0 = 0.f, ak1 = 0.f, ak2 = 0.f, ak3 = 0.f;
    int o = lane * 4;
    const float av[4] = {a.x, a.y, a.z, a.w};
#pragma unroll
    for (int j = 0; j < 4; ++j) {
        float4 qv = *(const float4*)(q + (o + j) * 4);
        float4 kv = *(const float4*)(kmat + (o + j) * 4);
        aq0 += av[j] * qv.x; aq1 += av[j] * qv.y;
        aq2 += av[j] * qv.z; aq3 += av[j] * qv.w;
        ak0 += av[j] * kv.x; ak1 += av[j] * kv.y;
        ak2 += av[j] * kv.z; ak3 += av[j] * kv.w;
    }
#pragma unroll
    for (int d = 1; d < 64; d <<= 1) {
        aq0 += __shfl_xor(aq0, d); aq1 += __shfl_xor(aq1, d);
        aq2 += __shfl_xor(aq2, d); aq3 += __shfl_xor(aq3, d);
        ak0 += __shfl_xor(ak0, d); ak1 += __shfl_xor(ak1, d);
        ak2 += __shfl_xor(ak2, d); ak3 += __shfl_xor(ak3, d);
    }
    if (lane == 0) {
        int nq = r * 4, nk = 32 + r * 4;
        wqkb[(nq + 0) * 256 + i] = f2bf(aq0);
        wqkb[(nq + 1) * 256 + i] = f2bf(aq1);
        wqkb[(nq + 2) * 256 + i] = f2bf(aq2);
        wqkb[(nq + 3) * 256 + i] = f2bf(aq3);
        wqkb[(nk + 0) * 256 + i] = f2bf(ak0);
        wqkb[(nk + 1) * 256 + i] = f2bf(ak1);
        wqkb[(nk + 2) * 256 + i] = f2bf(ak2);
        wqkb[(nk + 3) * 256 + i] = f2bf(ak3);
    }
}

// qn|kn = xb @ wqkb^T via MFMA.  Block: 256 thr = 4 waves, 64 rows per block.
#define QP 264
__global__ __launch_bounds__(256) void k_qnkn_mfma(
    const unsigned short* __restrict__ xb, const unsigned short* __restrict__ wqkb,
    float* __restrict__ qn, float* __restrict__ kn)
{
    __shared__ unsigned short Ws[64 * QP];
    int t = threadIdx.x;
    {
        int r = t >> 2, off = (t & 3) * 64;
#pragma unroll
        for (int i = 0; i < 8; ++i)
            *(uint4*)(&Ws[r * QP + off + i * 8]) =
                *(const uint4*)(wqkb + r * 256 + off + i * 8);
    }
    __syncthreads();
    int wave = t >> 6, lane = t & 63;
    int lrow = lane & 15, kq = lane >> 4;
    int mw = blockIdx.x * 64 + wave * 16;
    int gm = mw + lrow;
    int gmc = gm < N ? gm : N - 1;

    f32x4 acc[4];
#pragma unroll
    for (int j = 0; j < 4; ++j) acc[j] = (f32x4){0.f, 0.f, 0.f, 0.f};

    for (int k0 = 0; k0 < 8; ++k0) {
        short8 af = *(const short8*)(xb + (size_t)gmc * 256 + k0 * 32 + kq * 8);
#pragma unroll
        for (int j = 0; j < 4; ++j) {
            short8 bf4 = *(const short8*)(&Ws[(j * 16 + lrow) * QP + k0 * 32 + kq * 8]);
            acc[j] = __builtin_amdgcn_mfma_f32_16x16x32_bf16(af, bf4, acc[j], 0, 0, 0);
        }
    }
#pragma unroll
    for (int j = 0; j < 4; ++j) {
        int col = j * 16 + lrow;
#pragma unroll
        for (int reg = 0; reg < 4; ++reg) {
            int gr = mw + kq * 4 + reg;
            if (gr < N) {
                if (col < 32) qn[gr * 32 + col] = acc[j][reg];
                else          kn[gr * 32 + (col - 32)] = acc[j][reg];
            }
        }
    }
}

// wave-per-node softmax: lanes = 16 edge-slots x 4 heads, shuffle reductions.
__global__ void k_soft(const int* __restrict__ rowptr, const int* __restrict__ csr_se,
                       const int* __restrict__ csr_eid,
                       const float* __restrict__ qn, const float* __restrict__ kn,
                       float* __restrict__ alpha_csr, float* __restrict__ aout) {
    int wid = (blockIdx.x * blockDim.x + threadIdx.x) >> 6;
    int lane = threadIdx.x & 63;
    if (wid >= N) return;
    int d = wid;
    int beg = rowptr[d], end = rowptr[d + 1];
    if (beg >= end) return;
    int slot = lane >> 2, h = lane & 3;
    int nc = (end - beg + 15) >> 4;
    const float* qrow = qn + d * 32;

    auto rawv = [&](int i) {
        int se = csr_se[i];
        int tt = se >> 16, s = se & 0xFFFF;
        return lrelu(qrow[tt * 4 + h] + kn[s * 32 + tt * 4 + h], 0.2f);
    };

    float av[4];
    float m = -1e30f;
    for (int c = 0; c < nc; ++c) {
        int i = beg + c * 16 + slot;
        float v = (i < end) ? rawv(i) : -1e30f;
        if (c < 4) av[c] = v;
        m = fmaxf(m, v);
    }
    m = fmaxf(m, __shfl_xor(m, 4));
    m = fmaxf(m, __shfl_xor(m, 8));
    m = fmaxf(m, __shfl_xor(m, 16));
    m = fmaxf(m, __shfl_xor(m, 32));

    float sum = 0.f;
    for (int c = 0; c < nc; ++c) {
        int i = beg + c * 16 + slot;
        float ex = 0.f;
        if (i < end) {
            float v = (c < 4) ? av[c] : rawv(i);
            ex = expf(v - m);
        }
        if (c < 4) av[c] = ex;
        sum += ex;
    }
    sum += __shfl_xor(sum, 4);
    sum += __shfl_xor(sum, 8);
    sum += __shfl_xor(sum, 16);
    sum += __shfl_xor(sum, 32);
    float inv = 1.f / sum;

    for (int c = 0; c < nc; ++c) {
        int i = beg + c * 16 + slot;
        if (i < end) {
            float ex = (c < 4) ? av[c] : expf(rawv(i) - m);
            float a = ex * inv;
            alpha_csr[i * 4 + h] = a;
            aout[csr_eid[i] * 4 + h] = a;
        }
    }
}

// Wt[z][n][k] = bf16(W[z][k][n])  -- 64x64 LDS-tile transpose, coalesced both ways
#define WTP 72
__global__ __launch_bounds__(256) void k_wconv_t(const float* __restrict__ W,
                                                 unsigned short* __restrict__ Wt) {
    int bid = blockIdx.x;
    int z = bid >> 4;
    int tile = bid & 15;
    int k0 = (tile >> 2) * 64, n0 = (tile & 3) * 64;
    __shared__ unsigned short T[64 * WTP];
    int t = threadIdx.x;
    const float* Wz = W + ((size_t)z << 16);
    int r = t >> 4;
    int cs = (t & 15) * 4;
#pragma unroll
    for (int rr = 0; rr < 4; ++rr) {
        int k = r + rr * 16;
        float4 v = *(const float4*)(Wz + (size_t)(k0 + k) * 256 + n0 + cs);
        T[(cs + 0) * WTP + k] = f2bf(v.x);
        T[(cs + 1) * WTP + k] = f2bf(v.y);
        T[(cs + 2) * WTP + k] = f2bf(v.z);
        T[(cs + 3) * WTP + k] = f2bf(v.w);
    }
    __syncthreads();
    int n = t >> 2, ck = (t & 3) * 16;
    unsigned short* dst = Wt + ((size_t)z << 16) + (size_t)(n0 + n) * 256 + k0 + ck;
    const unsigned short* srcp = T + n * WTP + ck;
    *(uint4*)(dst) = *(const uint4*)(srcp);
    *(uint4*)(dst + 8) = *(const uint4*)(srcp + 8);
}

// ---------------- bf16 MFMA GEMM: 512 thr, 8 waves of 64x32, XCD-swizzled ------
// z < zlin (or zlin<0): Cbf[z][M][256] = bf16(A@B[z])
// z == zlin          : Cf = A@B[z] + bias + bias2   (fp32, full store)
#define TM 128
#define TN 128
#define TK 32
#define LPP 40
__global__ __launch_bounds__(512) void gemm_mfma4(
    const unsigned short* __restrict__ A, const unsigned short* __restrict__ Bt,
    unsigned short* __restrict__ Cbf, float* __restrict__ Cf,
    const float* __restrict__ bias, const float* __restrict__ bias2,
    int M, int NZ, int NT, int MT, int zlin)
{
    __shared__ unsigned short As[TM * LPP];
    __shared__ unsigned short Bs[TN * LPP];

    int bi = blockIdx.x;
    int cx = bi & 7;
    int g = bi >> 3;
    int per = NZ * NT;
    int mh = g / per;
    int j  = g % per;
    int mt = mh * 8 + cx;
    if (mt >= MT) return;
    int z  = j % NZ;
    int nb = j / NZ;
    int m0 = mt * TM;
    int n0 = nb * TN;

    const unsigned short* Bz = Bt + ((size_t)z << 16);
    int t = threadIdx.x;
    int wave = t >> 6, lane = t & 63;
    int wr = wave >> 2;      // 0..1 : 64-row half
    int wc = wave & 3;       // 0..3 : 32-col block
    int lrow = lane & 15, kq = lane >> 4;
    int srow = t >> 2, skc = t & 3;

    f32x4 acc[4][2];
#pragma unroll
    for (int i = 0; i < 4; ++i)
#pragma unroll
        for (int jj = 0; jj < 2; ++jj) acc[i][jj] = (f32x4){0.f, 0.f, 0.f, 0.f};

    for (int k0 = 0; k0 < 256; k0 += TK) {
        {
            int gm = m0 + srow;
            uint4 va = {0, 0, 0, 0};
            if (gm < M) va = *(const uint4*)(A + (size_t)gm * 256 + k0 + skc * 8);
            *(uint4*)(&As[srow * LPP + skc * 8]) = va;
            uint4 vb = *(const uint4*)(Bz + (size_t)(n0 + srow) * 256 + k0 + skc * 8);
            *(uint4*)(&Bs[srow * LPP + skc * 8]) = vb;
        }
        __syncthreads();
        short8 af[4], bf4[2];
#pragma unroll
        for (int i = 0; i < 4; ++i)
            af[i] = *(const short8*)(&As[(wr * 64 + i * 16 + lrow) * LPP + kq * 8]);
#pragma unroll
        for (int jj = 0; jj < 2; ++jj)
            bf4[jj] = *(const short8*)(&Bs[(wc * 32 + jj * 16 + lrow) * LPP + kq * 8]);
#pragma unroll
        for (int i = 0; i < 4; ++i)
#pragma unroll
            for (int jj = 0; jj < 2; ++jj)
                acc[i][jj] = __builtin_amdgcn_mfma_f32_16x16x32_bf16(af[i], bf4[jj],
                                                                     acc[i][jj], 0, 0, 0);
        __syncthreads();
    }
    // C/D layout: row = quad*4 + reg, col = lane&15
    if (z == zlin) {
#pragma unroll
        for (int i = 0; i < 4; ++i)
#pragma unroll
            for (int jj = 0; jj < 2; ++jj) {
                int gn = n0 + wc * 32 + jj * 16 + lrow;
                float bsum = bias[gn] + bias2[gn];
#pragma unroll
                for (int reg = 0; reg < 4; ++reg) {
                    int gm = m0 + wr * 64 + i * 16 + kq * 4 + reg;
                    if (gm < M) Cf[(size_t)gm * 256 + gn] = acc[i][jj][reg] + bsum;
                }
            }
    } else {
#pragma unroll
        for (int i = 0; i < 4; ++i)
#pragma unroll
            for (int jj = 0; jj < 2; ++jj) {
                int gn = n0 + wc * 32 + jj * 16 + lrow;
#pragma unroll
                for (int reg = 0; reg < 4; ++reg) {
                    int gm = m0 + wr * 64 + i * 16 + kq * 4 + reg;
                    if (gm < M)
                        Cbf[((size_t)z * M + gm) * 256 + gn] = f2bf(acc[i][jj][reg]);
                }
            }
    }
}

// ---------------- message aggregation: 2 waves per node, LDS combine ----------
// Block 256 thr = 4 waves = 2 nodes; wave parity p handles edges beg+p, beg+p+2, ...
__global__ __launch_bounds__(256) void k_msg_gather(
    const int* __restrict__ rowptr, const int* __restrict__ csr_se,
    const float* __restrict__ alpha_csr, const unsigned short* __restrict__ xw,
    const float* __restrict__ bias, float* __restrict__ out,
    unsigned short* __restrict__ xbout, int r0, int r1, int first, int act) {
    __shared__ float Pf[2][256];
    int tid = threadIdx.x;
    int wave = tid >> 6, lane = tid & 63;
    int nslot = wave >> 1, p = wave & 1;
    int node = blockIdx.x * 2 + nslot;
    int hsel = lane >> 4;
    float ax = 0.f, ay = 0.f, az = 0.f, aw = 0.f;

    auto edge = [&](int i) {
        int se = csr_se[i];
        int tt = se >> 16;
        if (tt >= r0 && tt < r1) {
            int s = se & 0xFFFF;
            float a = alpha_csr[i * 4 + hsel];
            uint2 pv = *(const uint2*)(xw + ((size_t)(tt - r0) * N + s) * 256 + lane * 4);
            ax += a * __uint_as_float(pv.x << 16);
            ay += a * __uint_as_float(pv.x & 0xFFFF0000u);
            az += a * __uint_as_float(pv.y << 16);
            aw += a * __uint_as_float(pv.y & 0xFFFF0000u);
        }
    };

    if (node < N) {
        int beg = rowptr[node], end = rowptr[node + 1];
        int i = beg + p;
        for (; i + 2 < end; i += 4) { edge(i); edge(i + 2); }
        if (i < end) edge(i);
    }
    if (p == 1) {
        float4 v = {ax, ay, az, aw};
        *(float4*)(&Pf[nslot][lane * 4]) = v;
    }
    __syncthreads();
    if (p == 0 && node < N) {
        float4 q = *(const float4*)(&Pf[nslot][lane * 4]);
        ax += q.x; ay += q.y; az += q.z; aw += q.w;
        float* o = out + (size_t)node * 256 + lane * 4;
        float vx, vy, vz, vw;
        if (first) {
            const float4 b = ((const float4*)bias)[lane];
            vx = ax + b.x; vy = ay + b.y; vz = az + b.z; vw = aw + b.w;
        } else {
            vx = o[0] + ax; vy = o[1] + ay; vz = o[2] + az; vw = o[3] + aw;
        }
        if (act) {
            vx = lrelu(vx, 0.01f); vy = lrelu(vy, 0.01f);
            vz = lrelu(vz, 0.01f); vw = lrelu(vw, 0.01f);
            unsigned short* xo = xbout + (size_t)node * 256 + lane * 4;
            xo[0] = f2bf(vx); xo[1] = f2bf(vy); xo[2] = f2bf(vz); xo[3] = f2bf(vw);
        }
        o[0] = vx; o[1] = vy; o[2] = vz; o[3] = vw;
    }
}

extern "C" void kernel_launch(void* const* d_in, const int* in_sizes, int n_in,
                              void* d_out, int out_size, void* d_ws, size_t ws_size,
                              hipStream_t stream) {
    const float* kg   = (const float*)d_in[0];
    const float* cc0  = (const float*)d_in[1];
    const float* gw1  = (const float*)d_in[2];
    const float* gb1  = (const float*)d_in[3];
    const float* gw2  = (const float*)d_in[4];
    const float* gb2  = (const float*)d_in[5];
    const float* r1w  = (const float*)d_in[6];
    const float* r1q  = (const float*)d_in[7];
    const float* r1k  = (const float*)d_in[8];
    const float* r1b  = (const float*)d_in[9];
    const float* r2w  = (const float*)d_in[10];
    const float* r2q  = (const float*)d_in[11];
    const float* r2k  = (const float*)d_in[12];
    const float* r2b  = (const float*)d_in[13];
    const float* linw = (const float*)d_in[14];
    const float* linb = (const float*)d_in[15];
    const int*   ei   = (const int*)d_in[16];
    const int*   et   = (const int*)d_in[17];

    float* out = (float*)d_out;
    float* a1  = out + (size_t)N * C;
    float* a2  = a1 + (size_t)E * H;

    float* ws = (float*)d_ws;
    size_t off = 0;
    float* dis  = ws + off; off += N;
    float* h1   = ws + off; off += (size_t)N * 32;
    float* c1   = ws + off; off += (size_t)N * 32;
    unsigned short* h2b = (unsigned short*)(ws + off); off += (size_t)N * 64;
    float* x0   = ws + off; off += (size_t)N * C;
    float* hmid = ws + off; off += (size_t)N * C;
    float* qn   = ws + off; off += (size_t)N * R * H;
    float* kn   = ws + off; off += (size_t)N * R * H;
    int* cnt     = (int*)(ws + off); off += N;
    int* rowptr  = (int*)(ws + off); off += N + 1;
    int* cursor  = (int*)(ws + off); off += N;
    int* csr_se  = (int*)(ws + off); off += E;
    int* csr_eid = (int*)(ws + off); off += E;
    float* alpha = ws + off; off += (size_t)E * H;
    unsigned short* xb0 = (unsigned short*)(ws + off); off += (size_t)N * 128;
    unsigned short* xb1 = (unsigned short*)(ws + off); off += (size_t)N * 128;
    // wt[0..R-1] = RGAT weights (transposed bf16); wt[R] = lin weight -> contiguous
    unsigned short* wt  = (unsigned short*)(ws + off); off += (size_t)(R + 1) * 32768;
    unsigned short* wtl = wt + ((size_t)R << 16);
    unsigned short* wqkb = (unsigned short*)(ws + off); off += 8192;
    unsigned short* xwb = (unsigned short*)(ws + off);

    size_t fixedB = off * 4;
    int K = R;
    if (ws_size > fixedB) {
        size_t kmax = (ws_size - fixedB) / ((size_t)N * C * 2);
        if (kmax < (size_t)K) K = (int)kmax;
    } else {
        K = 1;
    }
    if (K < 1) K = 1;

    const int B = 256;
    auto cdiv = [](long a, long b) { return (int)((a + b - 1) / b); };
    const int MT = cdiv(N, TM);  // 157 m-tiles
    const int NT = C / TN;       // 2

    // ---- CSR build ----
    k_zero_int<<<cdiv(N, B), B, 0, stream>>>(cnt, N);
    k_count<<<cdiv(E, B), B, 0, stream>>>(ei, cnt);
    k_scan<<<1, 1024, 0, stream>>>(cnt, rowptr, cursor, dis);
    k_scatter<<<cdiv(E, B), B, 0, stream>>>(ei, et, cursor, csr_se, csr_eid);

    // ---- GCN ----
    k_h1<<<cdiv((long)N * 32, B), B, 0, stream>>>(cc0, gw1, h1);
    k_agg32<<<cdiv((long)N * 32, B), B, 0, stream>>>(rowptr, csr_se, dis, h1, gb1, c1);
    k_h2kg<<<cdiv((long)N * 128, B), B, 0, stream>>>(c1, gw2, kg, h2b, x0, xb0);
    k_agg128<<<cdiv((long)N * 128, B), B, 0, stream>>>(rowptr, csr_se, dis, h2b,
                                                       gb2, x0, xb0);

    auto rgat = [&](unsigned short* xb, const float* W,
                    const float* q, const float* kk, const float* b,
                    float* obuf, unsigned short* xbout, float* aout,
                    int first, int act, int lin, float* linout,
                    const float* lb1, const float* lb2) {
        k_wqkb<<<512, 256, 0, stream>>>(W, q, kk, wqkb);
        k_qnkn_mfma<<<cdiv(N, 64), B, 0, stream>>>(xb, wqkb, qn, kn);
        k_soft<<<cdiv((long)N * 64, B), B, 0, stream>>>(rowptr, csr_se, csr_eid,
                                                        qn, kn, alpha, aout);
        k_wconv_t<<<R * 16, 256, 0, stream>>>(W, wt);
        for (int r0 = 0; r0 < R; r0 += K) {
            int kc = (R - r0) < K ? (R - r0) : K;
            int addlin = (lin && (r0 + kc == R)) ? 1 : 0;
            int nz = kc + addlin;
            int zl = addlin ? kc : -1;
            int gx = 8 * nz * NT * cdiv(MT, 8);
            gemm_mfma4<<<gx, 512, 0, stream>>>(xb, wt + ((size_t)r0 << 16), xwb,
                                               linout, lb1, lb2,
                                               N, nz, NT, MT, zl);
            int last = (r0 + kc >= R) ? 1 : 0;
            k_msg_gather<<<cdiv(N, 2), 256, 0, stream>>>(
                rowptr, csr_se, alpha, xwb, b, obuf, xbout, r0, r0 + kc,
                (first && r0 == 0) ? 1 : 0, act && last);
        }
    };

    // residual-linear weight transposed into wt[R] before layer 1
    k_wconv_t<<<16, 256, 0, stream>>>(linw, wtl);

    // layer 1: hmid = r1b + messages (leaky fused, emits xb1 bf16);
    //          merged z=8 slice writes out = x0@linw + (linb + r2b)
    rgat(xb0, r1w, r1q, r1k, r1b, hmid, xb1, a1, 1, 1,
         1, out, linb, r2b);

    // layer 2: out += messages (bias already folded into linear epilogue)
    rgat(xb1, r2w, r2q, r2k, r2b, out, nullptr, a2, 0, 0,
         0, nullptr, nullptr, nullptr);
}